// Round 6
// baseline (450.224 us; speedup 1.0000x reference)
//
#include <hip/hip_runtime.h>
#include <hip/hip_bf16.h>

typedef __hip_bfloat16 bf16;
typedef short bf16x8 __attribute__((ext_vector_type(8)));
typedef float f32x4 __attribute__((ext_vector_type(4)));

#define BBATCH 8
#define HHH 56
#define WWW 56
#define CCH 96          // C
#define DIN 192         // D
#define NST 16          // N
#define KDIR 4          // K
#define RDT 6           // R
#define LLEN 3136       // H*W
#define BLTOT 25088     // B*L
#define SSEG 112        // segments (112 * 28 = 3136)
#define SEGL 28         // L / SSEG
#define PJC 38          // R + 2N
#define PJW 152         // K * PJC
#define PJS 40          // padded LDS row stride (16B aligned)
#define PJS1 24         // corr-pass padded row stride (dt+C only)
#define MLPH 384

// native exp2/log2 (v_exp_f32 / v_log_f32) with safe fallbacks
#if defined(__has_builtin)
#if __has_builtin(__builtin_amdgcn_exp2f)
#define EXP2F(x) __builtin_amdgcn_exp2f(x)
#endif
#if __has_builtin(__builtin_amdgcn_logf)
#define LOG2F_(x) __builtin_amdgcn_logf(x)
#endif
#endif
#ifndef EXP2F
#define EXP2F(x) __expf((x) * 0.69314718056f)
#endif
#ifndef LOG2F_
#define LOG2F_(x) (__logf(x) * 1.44269504f)
#endif
#define LOG2E 1.44269504f

// packed fp32 (VOP3P, gfx90a+/gfx950). NOTE: all-VGPR operands only —
// an SGPR source on VOP3P is 32-bit and broadcast to BOTH packed
// components, which silently corrupts per-component math.
__device__ __forceinline__ float2 pk_mul(float2 a, float2 b) {
    float2 d;
    asm("v_pk_mul_f32 %0, %1, %2" : "=v"(d) : "v"(a), "v"(b));
    return d;
}
__device__ __forceinline__ float2 pk_fma(float2 a, float2 b, float2 c) {
    float2 d;
    asm("v_pk_fma_f32 %0, %1, %2, %3" : "=v"(d) : "v"(a), "v"(b), "v"(c));
    return d;
}

__device__ __forceinline__ float b2f(bf16 v) { return __bfloat162float(v); }
__device__ __forceinline__ bf16  f2b(float v) { return __float2bfloat16(v); }
__device__ __forceinline__ unsigned short f2bu(float f) {
    union { bf16 h; unsigned short u; } c; c.h = __float2bfloat16(f); return c.u;
}
__device__ __forceinline__ float bu2f(unsigned short u) {
    union { unsigned short u; bf16 h; } c; c.u = u; return __bfloat162float(c.h);
}
__device__ __forceinline__ float sigm(float x) { return 1.f / (1.f + __expf(-x)); }
__device__ __forceinline__ float softplusf(float x) {
    float t = EXP2F(-fabsf(x) * LOG2E);
    return fmaxf(x, 0.f) + 0.69314718f * LOG2F_(1.f + t);
}
__device__ __forceinline__ float geluf(float v) {
    float u = 0.7978845608028654f * (v + 0.044715f * v * v * v);
    float ey = __expf(2.f * u);
    float th = 1.f - 2.f / (ey + 1.f);
    return 0.5f * v * (1.f + th);
}

// scan-step l -> spatial position (row-major h*56+w) for direction k
__device__ __forceinline__ int pos_map(int k, int l) {
    if (k & 2) l = LLEN - 1 - l;
    if (k & 1) { int q = l / WWW; int r = l - q * WWW; return r * WWW + q; }
    return l;
}

// ---- K0: precompute a2[k][d][n] = -exp(Alog)*log2e --------------------------
__global__ __launch_bounds__(256) void k0_pre(
    const float* __restrict__ Alog, float* __restrict__ a2g) {
    int i = blockIdx.x * 256 + threadIdx.x;   // over K*D*N = 12288
    a2g[i] = -__expf(Alog[i]) * LOG2E;
}

// ---- K0w: pre-convert the 5 GEMM weight matrices to bf16 --------------------
// layout in wbf: inpW@0(36864) xprojW@36864(29184) outW@66048(18432)
//               fc1W@84480(36864) fc2W@121344(36864)  total 158208
__global__ __launch_bounds__(256) void k0w(
    const float* __restrict__ w1, const float* __restrict__ w2,
    const float* __restrict__ w3, const float* __restrict__ w4,
    const float* __restrict__ w5, unsigned short* __restrict__ o) {
    int i = blockIdx.x * 256 + threadIdx.x;
    float v;
    if (i < 36864)       v = w1[i];
    else if (i < 66048)  v = w2[i - 36864];
    else if (i < 84480)  v = w3[i - 66048];
    else if (i < 121344) v = w4[i - 84480];
    else                 v = w5[i - 121344];
    o[i] = f2bu(v);
}

// ---- Unified MFMA GEMM: C[M=25088][N] = A[M][K] . Wb[N][K]^T(bf16) ---------
// block: 4 waves, each wave a 32-row M-strip, 2x4 frags -> 128M x 64N tile.
// LNIN: A is f32 (K=96) with LayerNorm fused during staging.
// EPI: 0=split xc/z  1=proj f32  2=+res f32  3=gelu(+bias) bf16  4=+bias+res f32
template<int N, int K, int EPI, bool LNIN>
__global__ __launch_bounds__(256) void gemm_mfma(
    const void* __restrict__ Xv, const unsigned short* __restrict__ Wb,
    const float* __restrict__ bias, const float* __restrict__ res,
    const float* __restrict__ lnw, const float* __restrict__ lnb,
    void* __restrict__ out0v, void* __restrict__ out1v) {
    __shared__ unsigned short a_sh[128 * 40];
    __shared__ unsigned short b_sh[64 * 40];
    __shared__ float mrow[128], rrow[128];
    __shared__ float lnw_sh[96], lnb_sh[96];
    const int t = threadIdx.x;
    const int P0 = blockIdx.x * 128;
    const int N0 = blockIdx.y * 64;
    const int w = t >> 6, lane = t & 63, q = lane >> 4, nl = lane & 15;
    if constexpr (LNIN) {
        // row stats: 2 threads per row, 48 elems each
        const float* Xf = (const float*)Xv;
        const float* xr = Xf + (size_t)(P0 + (t >> 1)) * 96 + (t & 1) * 48;
        float s = 0.f, s2 = 0.f;
#pragma unroll
        for (int i = 0; i < 12; ++i) {
            float4 v = *(const float4*)&xr[i * 4];
            s += v.x + v.y + v.z + v.w;
            s2 += v.x * v.x + v.y * v.y + v.z * v.z + v.w * v.w;
        }
        s += __shfl_xor(s, 1); s2 += __shfl_xor(s2, 1);
        if ((t & 1) == 0) {
            float m = s * (1.f / 96.f);
            float var = s2 * (1.f / 96.f) - m * m;
            mrow[t >> 1] = m; rrow[t >> 1] = rsqrtf(var + 1e-5f);
        }
        if (t < 96) { lnw_sh[t] = lnw[t]; lnb_sh[t] = lnb[t]; }
    }
    f32x4 acc[2][4];
#pragma unroll
    for (int i = 0; i < 2; ++i)
#pragma unroll
        for (int j = 0; j < 4; ++j)
            acc[i][j] = (f32x4){0.f, 0.f, 0.f, 0.f};
    for (int k0 = 0; k0 < K; k0 += 32) {
        __syncthreads();
        // stage A: 128 rows x 32 k
#pragma unroll
        for (int it = 0; it < 2; ++it) {
            int idx = t + it * 256;
            int pr = idx >> 2, kq = idx & 3;
            if constexpr (LNIN) {
                const float* Xf = (const float*)Xv;
                const float* src = &Xf[(size_t)(P0 + pr) * K + k0 + kq * 8];
                float m = mrow[pr], r = rrow[pr];
                float4 v0 = *(const float4*)src;
                float4 v1 = *(const float4*)(src + 4);
                int c0 = k0 + kq * 8;
                ushort4 u0, u1;
                u0.x = f2bu((v0.x - m) * r * lnw_sh[c0+0] + lnb_sh[c0+0]);
                u0.y = f2bu((v0.y - m) * r * lnw_sh[c0+1] + lnb_sh[c0+1]);
                u0.z = f2bu((v0.z - m) * r * lnw_sh[c0+2] + lnb_sh[c0+2]);
                u0.w = f2bu((v0.w - m) * r * lnw_sh[c0+3] + lnb_sh[c0+3]);
                u1.x = f2bu((v1.x - m) * r * lnw_sh[c0+4] + lnb_sh[c0+4]);
                u1.y = f2bu((v1.y - m) * r * lnw_sh[c0+5] + lnb_sh[c0+5]);
                u1.z = f2bu((v1.z - m) * r * lnw_sh[c0+6] + lnb_sh[c0+6]);
                u1.w = f2bu((v1.w - m) * r * lnw_sh[c0+7] + lnb_sh[c0+7]);
                *(ushort4*)&a_sh[pr * 40 + kq * 8] = u0;
                *(ushort4*)&a_sh[pr * 40 + kq * 8 + 4] = u1;
            } else {
                const unsigned short* X = (const unsigned short*)Xv;
                uint4 v = *(const uint4*)&X[(size_t)(P0 + pr) * K + k0 + kq * 8];
                *(uint4*)&a_sh[pr * 40 + kq * 8] = v;
            }
        }
        // stage B: 64 rows x 32 k (bf16 pass-through, 1 uint4/thread)
        {
            int nr = t >> 2, kq = t & 3;
            int ng = N0 + nr; if (ng > N - 1) ng = N - 1;
            uint4 v = *(const uint4*)&Wb[(size_t)ng * K + k0 + kq * 8];
            *(uint4*)&b_sh[nr * 40 + kq * 8] = v;
        }
        __syncthreads();
        bf16x8 af[2], bfr[4];
#pragma unroll
        for (int mf = 0; mf < 2; ++mf)
            af[mf] = *(const bf16x8*)&a_sh[(w * 32 + mf * 16 + nl) * 40 + q * 8];
#pragma unroll
        for (int nf = 0; nf < 4; ++nf)
            bfr[nf] = *(const bf16x8*)&b_sh[(nf * 16 + nl) * 40 + q * 8];
#pragma unroll
        for (int mf = 0; mf < 2; ++mf)
#pragma unroll
            for (int nf = 0; nf < 4; ++nf)
                acc[mf][nf] = __builtin_amdgcn_mfma_f32_16x16x32_bf16(
                    af[mf], bfr[nf], acc[mf][nf], 0, 0, 0);
    }
#pragma unroll
    for (int mf = 0; mf < 2; ++mf) {
#pragma unroll
        for (int nf = 0; nf < 4; ++nf) {
#pragma unroll
            for (int r = 0; r < 4; ++r) {
                float v = acc[mf][nf][r];
                size_t pos = (size_t)P0 + w * 32 + mf * 16 + q * 4 + r;
                int n = N0 + nf * 16 + nl;
                if constexpr (EPI == 0) {
                    unsigned short* xc = (unsigned short*)out0v;
                    unsigned short* zz = (unsigned short*)out1v;
                    if (n < 192) xc[pos * 192 + n] = f2bu(v);
                    else         zz[pos * 192 + (n - 192)] = f2bu(v);
                } else if constexpr (EPI == 1) {
                    if (n < 152) ((float*)out0v)[pos * 152 + n] = v;
                } else if constexpr (EPI == 2) {
                    if (n < 96) ((float*)out0v)[pos * 96 + n] = res[pos * 96 + n] + v;
                } else if constexpr (EPI == 3) {
                    ((unsigned short*)out0v)[pos * 384 + n] = f2bu(geluf(v + bias[n]));
                } else {
                    if (n < 96) ((float*)out0v)[pos * 96 + n] =
                        res[pos * 96 + n] + bias[n] + v;
                }
            }
        }
    }
}

// ---- K2: depthwise 3x3 conv + bias + silu, 4 channels/thread ---------------
__global__ __launch_bounds__(256) void k2_conv(
    const unsigned short* __restrict__ xcpre, const float* __restrict__ cw,
    const float* __restrict__ cb, unsigned short* __restrict__ xconv) {
    int idx = blockIdx.x * 256 + threadIdx.x;
    int dd = idx % 48;
    int P = idx / 48;
    int d0 = dd * 4;
    int b = P / LLEN, l = P - b * LLEN;
    int h = l / WWW, w = l - h * WWW;
    float acc0 = cb[d0], acc1 = cb[d0 + 1], acc2 = cb[d0 + 2], acc3 = cb[d0 + 3];
#pragma unroll
    for (int i = 0; i < 3; ++i) {
        int hh = h + i - 1;
        if (hh < 0 || hh >= HHH) continue;
#pragma unroll
        for (int j = 0; j < 3; ++j) {
            int ww = w + j - 1;
            if (ww < 0 || ww >= WWW) continue;
            ushort4 xv = *(const ushort4*)&xcpre[
                ((size_t)(b * LLEN + hh * WWW + ww)) * DIN + d0];
            acc0 = fmaf(bu2f(xv.x), cw[(d0 + 0) * 9 + i * 3 + j], acc0);
            acc1 = fmaf(bu2f(xv.y), cw[(d0 + 1) * 9 + i * 3 + j], acc1);
            acc2 = fmaf(bu2f(xv.z), cw[(d0 + 2) * 9 + i * 3 + j], acc2);
            acc3 = fmaf(bu2f(xv.w), cw[(d0 + 3) * 9 + i * 3 + j], acc3);
        }
    }
    acc0 = acc0 * sigm(acc0); acc1 = acc1 * sigm(acc1);
    acc2 = acc2 * sigm(acc2); acc3 = acc3 * sigm(acc3);
    ushort4 o;
    o.x = f2bu(acc0); o.y = f2bu(acc1); o.z = f2bu(acc2); o.w = f2bu(acc3);
    *(ushort4*)&xconv[(size_t)P * DIN + d0] = o;
}

// ---- K4: pass 1 — TWO directions per thread (2x ILP, latency-bound fix) ----
// Each block: batch b, direction pair {2kp, 2kp+1}, segment s. Per-thread:
// two independent recurrences interleaved. hloc/tsum keep (bk*SSEG+s) layout.
__global__ __launch_bounds__(192) void k4_scan1y(
    const bf16* __restrict__ xconv, const float* __restrict__ proj,
    const float* __restrict__ dtw, const float* __restrict__ dtb,
    const float* __restrict__ a2g, const float* __restrict__ Dsp,
    float* __restrict__ hloc, float* __restrict__ tsum,
    bf16* __restrict__ ysm) {
    __shared__ float pl0[SEGL * PJS], pl1[SEGL * PJS];
    __shared__ int posl0[SEGL], posl1[SEGL];
    const int bid = blockIdx.x;          // 1792 = (b*2+kp)*112 + s
    const int s = bid % SSEG;
    const int r = bid / SSEG;            // 0..15
    const int kp = r & 1, b = r >> 1;
    const int ka = kp * 2, kb = ka + 1;
    const int bka = b * 4 + ka, bkb = bka + 1;
    const int d = threadIdx.x;
    const int l0 = s * SEGL;
    for (int q = d; q < 2 * SEGL * PJC; q += 192) {
        int half = q / (SEGL * PJC);
        int qq = q - half * (SEGL * PJC);
        int st = qq / PJC, c = qq - st * PJC;
        int kk = half ? kb : ka;
        int p = pos_map(kk, l0 + st);
        int ofs = (c < 6) ? c : c + 2;
        float v = proj[(size_t)(b * LLEN + p) * PJW + kk * PJC + c];
        if (half) pl1[st * PJS + ofs] = v;
        else      pl0[st * PJS + ofs] = v;
    }
    if (d < SEGL) {
        posl0[d] = pos_map(ka, l0 + d) * DIN;
        posl1[d] = pos_map(kb, l0 + d) * DIN;
    }
    float w6a[RDT], w6b[RDT];
#pragma unroll
    for (int r2 = 0; r2 < RDT; ++r2) {
        w6a[r2] = dtw[(ka * DIN + d) * RDT + r2];
        w6b[r2] = dtw[(kb * DIN + d) * RDT + r2];
    }
    const float biasa = dtb[ka * DIN + d], biasb = dtb[kb * DIN + d];
    const float dsva = Dsp[ka * DIN + d], dsvb = Dsp[kb * DIN + d];
    float2 a2a[8], a2b[8];
#pragma unroll
    for (int j = 0; j < 8; ++j) {
        a2a[j] = *(const float2*)&a2g[(ka * DIN + d) * NST + 2 * j];
        a2b[j] = *(const float2*)&a2g[(kb * DIN + d) * NST + 2 * j];
    }
    float2 h2a[8], h2b[8];
#pragma unroll
    for (int j = 0; j < 8; ++j) {
        h2a[j] = make_float2(0.f, 0.f);
        h2b[j] = make_float2(0.f, 0.f);
    }
    float Ta = 0.f, Tb = 0.f;
    __syncthreads();
    const bf16* xg = xconv + (size_t)b * LLEN * DIN + d;
    bf16* ysga = ysm + ((size_t)bka * LLEN) * DIN + d;
    bf16* ysgb = ysm + ((size_t)bkb * LLEN) * DIN + d;
    for (int bt = 0; bt < 4; ++bt) {
        int offa[7], offb[7]; float xva[7], xvb[7];
#pragma unroll
        for (int i = 0; i < 7; ++i) { offa[i] = posl0[bt * 7 + i]; offb[i] = posl1[bt * 7 + i]; }
#pragma unroll
        for (int i = 0; i < 7; ++i) { xva[i] = b2f(xg[offa[i]]); xvb[i] = b2f(xg[offb[i]]); }
#pragma unroll
        for (int i = 0; i < 7; ++i) {
            const float* rowa = &pl0[(bt * 7 + i) * PJS];
            const float* rowb = &pl1[(bt * 7 + i) * PJS];
            float4 ga0 = *(const float4*)(rowa);
            float2 ga1 = *(const float2*)(rowa + 4);
            float4 gb0 = *(const float4*)(rowb);
            float2 gb1 = *(const float2*)(rowb + 4);
            float dta = biasa, dtb_ = biasb;
            dta = fmaf(ga0.x, w6a[0], dta); dta = fmaf(ga0.y, w6a[1], dta);
            dta = fmaf(ga0.z, w6a[2], dta); dta = fmaf(ga0.w, w6a[3], dta);
            dta = fmaf(ga1.x, w6a[4], dta); dta = fmaf(ga1.y, w6a[5], dta);
            dtb_ = fmaf(gb0.x, w6b[0], dtb_); dtb_ = fmaf(gb0.y, w6b[1], dtb_);
            dtb_ = fmaf(gb0.z, w6b[2], dtb_); dtb_ = fmaf(gb0.w, w6b[3], dtb_);
            dtb_ = fmaf(gb1.x, w6b[4], dtb_); dtb_ = fmaf(gb1.y, w6b[5], dtb_);
            dta = softplusf(dta); dtb_ = softplusf(dtb_);
            Ta += dta; Tb += dtb_;
            float2 dt2a = make_float2(dta, dta);
            float2 dt2b = make_float2(dtb_, dtb_);
            float2 u2a = make_float2(dta * xva[i], dta * xva[i]);
            float2 u2b = make_float2(dtb_ * xvb[i], dtb_ * xvb[i]);
            float2 ya0 = make_float2(0.f, 0.f), ya1 = make_float2(0.f, 0.f);
            float2 yb0 = make_float2(0.f, 0.f), yb1 = make_float2(0.f, 0.f);
#pragma unroll
            for (int g = 0; g < 4; ++g) {
                float4 Bva = *(const float4*)(rowa + 8 + 4 * g);
                float4 Cva = *(const float4*)(rowa + 24 + 4 * g);
                float4 Bvb = *(const float4*)(rowb + 8 + 4 * g);
                float4 Cvb = *(const float4*)(rowb + 24 + 4 * g);
                float2 alo = pk_mul(dt2a, a2a[2 * g]);
                float2 ahi = pk_mul(dt2a, a2a[2 * g + 1]);
                float2 blo = pk_mul(dt2b, a2b[2 * g]);
                float2 bhi = pk_mul(dt2b, a2b[2 * g + 1]);
                float2 ealo, eahi, eblo, ebhi;
                ealo.x = EXP2F(alo.x); ealo.y = EXP2F(alo.y);
                eahi.x = EXP2F(ahi.x); eahi.y = EXP2F(ahi.y);
                eblo.x = EXP2F(blo.x); eblo.y = EXP2F(blo.y);
                ebhi.x = EXP2F(bhi.x); ebhi.y = EXP2F(bhi.y);
                h2a[2 * g]     = pk_fma(h2a[2 * g],     ealo,
                                        pk_mul(u2a, make_float2(Bva.x, Bva.y)));
                h2a[2 * g + 1] = pk_fma(h2a[2 * g + 1], eahi,
                                        pk_mul(u2a, make_float2(Bva.z, Bva.w)));
                h2b[2 * g]     = pk_fma(h2b[2 * g],     eblo,
                                        pk_mul(u2b, make_float2(Bvb.x, Bvb.y)));
                h2b[2 * g + 1] = pk_fma(h2b[2 * g + 1], ebhi,
                                        pk_mul(u2b, make_float2(Bvb.z, Bvb.w)));
                ya0 = pk_fma(h2a[2 * g],     make_float2(Cva.x, Cva.y), ya0);
                ya1 = pk_fma(h2a[2 * g + 1], make_float2(Cva.z, Cva.w), ya1);
                yb0 = pk_fma(h2b[2 * g],     make_float2(Cvb.x, Cvb.y), yb0);
                yb1 = pk_fma(h2b[2 * g + 1], make_float2(Cvb.z, Cvb.w), yb1);
            }
            float ya = (ya0.x + ya0.y) + (ya1.x + ya1.y);
            float yb = (yb0.x + yb0.y) + (yb1.x + yb1.y);
            ysga[offa[i]] = f2b(fmaf(dsva, xva[i], ya));
            ysgb[offb[i]] = f2b(fmaf(dsvb, xvb[i], yb));
        }
    }
    size_t basea = ((size_t)(bka * SSEG + s) * DIN + d) * NST;
    size_t baseb = ((size_t)(bkb * SSEG + s) * DIN + d) * NST;
#pragma unroll
    for (int j = 0; j < 8; ++j) {
        *(float2*)&hloc[basea + 2 * j] = h2a[j];
        *(float2*)&hloc[baseb + 2 * j] = h2b[j];
    }
    tsum[(bka * SSEG + s) * DIN + d] = Ta;
    tsum[(bkb * SSEG + s) * DIN + d] = Tb;
}

// ---- K5: exact segment carries (hin aliases hloc: read-before-write) -------
__global__ __launch_bounds__(256) void k5_carry(
    const float* hloc, const float* __restrict__ tsum,
    const float* __restrict__ a2g, float* hin) {
    int g = blockIdx.x * 256 + threadIdx.x;   // over B*K*D*N
    int n = g & 15;
    int dk = g >> 4;
    int d = dk % DIN;
    int bk = dk / DIN;                        // b*4 + k
    int k = bk & 3;
    float a2 = a2g[(k * DIN + d) * NST + n];
    float Hc = 0.f;
    for (int s = 0; s < SSEG; ++s) {
        int bid = bk * SSEG + s;
        size_t idx = ((size_t)bid * DIN + d) * NST + n;
        float hl = hloc[idx];
        float Tv = tsum[bid * DIN + d];
        hin[idx] = Hc;
        Hc = fmaf(EXP2F(a2 * Tv), Hc, hl);
    }
}

// ---- K6: pass 2 — carry correction, TWO directions per thread --------------
// y_l += C_l . (exp2(a2*cumT_l) * hin);  no h-chain, no B, no xconv.
__global__ __launch_bounds__(192) void k6_corr(
    const float* __restrict__ proj,
    const float* __restrict__ dtw, const float* __restrict__ dtb,
    const float* __restrict__ a2g, const float* __restrict__ hin,
    bf16* __restrict__ ysm) {
    __shared__ float pl0[SEGL * PJS1], pl1[SEGL * PJS1];
    __shared__ int posl0[SEGL], posl1[SEGL];
    const int bid = blockIdx.x;          // 1792
    const int s = bid % SSEG;
    const int r = bid / SSEG;
    const int kp = r & 1, b = r >> 1;
    const int ka = kp * 2, kb = ka + 1;
    const int bka = b * 4 + ka, bkb = bka + 1;
    const int d = threadIdx.x;
    const int l0 = s * SEGL;
    // stage dt channels (0..5) and C channels (22..37) -> LDS {0..5, 8..23}
    for (int q = d; q < 2 * SEGL * 22; q += 192) {
        int half = q / (SEGL * 22);
        int qq = q - half * (SEGL * 22);
        int st = qq / 22, c = qq - st * 22;
        int kk = half ? kb : ka;
        int p = pos_map(kk, l0 + st);
        int ch  = (c < 6) ? c : c + 16;
        int ofs = (c < 6) ? c : c + 2;
        float v = proj[(size_t)(b * LLEN + p) * PJW + kk * PJC + ch];
        if (half) pl1[st * PJS1 + ofs] = v;
        else      pl0[st * PJS1 + ofs] = v;
    }
    if (d < SEGL) {
        posl0[d] = pos_map(ka, l0 + d) * DIN;
        posl1[d] = pos_map(kb, l0 + d) * DIN;
    }
    float w6a[RDT], w6b[RDT];
#pragma unroll
    for (int r2 = 0; r2 < RDT; ++r2) {
        w6a[r2] = dtw[(ka * DIN + d) * RDT + r2];
        w6b[r2] = dtw[(kb * DIN + d) * RDT + r2];
    }
    const float biasa = dtb[ka * DIN + d], biasb = dtb[kb * DIN + d];
    float2 a2a[8], a2b[8];
#pragma unroll
    for (int j = 0; j < 8; ++j) {
        a2a[j] = *(const float2*)&a2g[(ka * DIN + d) * NST + 2 * j];
        a2b[j] = *(const float2*)&a2g[(kb * DIN + d) * NST + 2 * j];
    }
    float2 hina[8], hinb[8];
    size_t hbasea = ((size_t)(bka * SSEG + s) * DIN + d) * NST;
    size_t hbaseb = ((size_t)(bkb * SSEG + s) * DIN + d) * NST;
#pragma unroll
    for (int j = 0; j < 8; ++j) {
        hina[j] = *(const float2*)&hin[hbasea + 2 * j];
        hinb[j] = *(const float2*)&hin[hbaseb + 2 * j];
    }
    __syncthreads();
    bf16* ysga = ysm + ((size_t)bka * LLEN) * DIN + d;
    bf16* ysgb = ysm + ((size_t)bkb * LLEN) * DIN + d;
    float cTa = 0.f, cTb = 0.f;
    for (int bt = 0; bt < 4; ++bt) {
        int offa[7], offb[7];
#pragma unroll
        for (int i = 0; i < 7; ++i) { offa[i] = posl0[bt * 7 + i]; offb[i] = posl1[bt * 7 + i]; }
#pragma unroll
        for (int i = 0; i < 7; ++i) {
            const float* rowa = &pl0[(bt * 7 + i) * PJS1];
            const float* rowb = &pl1[(bt * 7 + i) * PJS1];
            float4 ga0 = *(const float4*)(rowa);
            float2 ga1 = *(const float2*)(rowa + 4);
            float4 gb0 = *(const float4*)(rowb);
            float2 gb1 = *(const float2*)(rowb + 4);
            float dta = biasa, dtb_ = biasb;
            dta = fmaf(ga0.x, w6a[0], dta); dta = fmaf(ga0.y, w6a[1], dta);
            dta = fmaf(ga0.z, w6a[2], dta); dta = fmaf(ga0.w, w6a[3], dta);
            dta = fmaf(ga1.x, w6a[4], dta); dta = fmaf(ga1.y, w6a[5], dta);
            dtb_ = fmaf(gb0.x, w6b[0], dtb_); dtb_ = fmaf(gb0.y, w6b[1], dtb_);
            dtb_ = fmaf(gb0.z, w6b[2], dtb_); dtb_ = fmaf(gb0.w, w6b[3], dtb_);
            dtb_ = fmaf(gb1.x, w6b[4], dtb_); dtb_ = fmaf(gb1.y, w6b[5], dtb_);
            dta = softplusf(dta); dtb_ = softplusf(dtb_);
            cTa += dta; cTb += dtb_;
            float2 ct2a = make_float2(cTa, cTa);
            float2 ct2b = make_float2(cTb, cTb);
            float2 ya0 = make_float2(0.f, 0.f), ya1 = make_float2(0.f, 0.f);
            float2 yb0 = make_float2(0.f, 0.f), yb1 = make_float2(0.f, 0.f);
#pragma unroll
            for (int g = 0; g < 4; ++g) {
                float2 Cla = *(const float2*)(rowa + 8 + 4 * g);
                float2 Cha = *(const float2*)(rowa + 8 + 4 * g + 2);
                float2 Clb = *(const float2*)(rowb + 8 + 4 * g);
                float2 Chb = *(const float2*)(rowb + 8 + 4 * g + 2);
                float2 alo = pk_mul(ct2a, a2a[2 * g]);
                float2 ahi = pk_mul(ct2a, a2a[2 * g + 1]);
                float2 blo = pk_mul(ct2b, a2b[2 * g]);
                float2 bhi = pk_mul(ct2b, a2b[2 * g + 1]);
                float2 palo, pahi, pblo, pbhi;
                palo.x = EXP2F(alo.x); palo.y = EXP2F(alo.y);
                pahi.x = EXP2F(ahi.x); pahi.y = EXP2F(ahi.y);
                pblo.x = EXP2F(blo.x); pblo.y = EXP2F(blo.y);
                pbhi.x = EXP2F(bhi.x); pbhi.y = EXP2F(bhi.y);
                float2 mal = pk_mul(palo, hina[2 * g]);
                float2 mah = pk_mul(pahi, hina[2 * g + 1]);
                float2 mbl = pk_mul(pblo, hinb[2 * g]);
                float2 mbh = pk_mul(pbhi, hinb[2 * g + 1]);
                ya0 = pk_fma(mal, Cla, ya0);
                ya1 = pk_fma(mah, Cha, ya1);
                yb0 = pk_fma(mbl, Clb, yb0);
                yb1 = pk_fma(mbh, Chb, yb1);
            }
            float corra = (ya0.x + ya0.y) + (ya1.x + ya1.y);
            float corrb = (yb0.x + yb0.y) + (yb1.x + yb1.y);
            int oa = offa[i], ob = offb[i];
            ysga[oa] = f2b(b2f(ysga[oa]) + corra);
            ysgb[ob] = f2b(b2f(ysgb[ob]) + corrb);
        }
    }
}

// ---- K6.5: merge 4 planes + out_norm LN + *silu(z), 8-wide bf16 vecio ------
__global__ __launch_bounds__(256) void k65_merge(
    const bf16* __restrict__ ysm, const bf16* __restrict__ z,
    const float* __restrict__ onw, const float* __restrict__ onb,
    bf16* __restrict__ ymod) {
    __shared__ float rb[16 * DIN];
    __shared__ float ps[256], pq[256];
    __shared__ float mrow[16], srow[16];
    const int t = threadIdx.x;
    const int P0 = blockIdx.x * 16;
    // fill: 384 groups of 8 channels (uint4 = 8 bf16 per plane)
    for (int q8 = t; q8 < 16 * DIN / 8; q8 += 256) {
        int pos = q8 / 24, c = (q8 - pos * 24) * 8;
        int P = P0 + pos;
        int b = P / LLEN, l = P - b * LLEN;
        size_t base = ((size_t)(b * KDIR) * LLEN + l) * DIN + c;
        size_t pstr = (size_t)LLEN * DIN;
        uint4 v0 = *(const uint4*)&ysm[base];
        uint4 v1 = *(const uint4*)&ysm[base + pstr];
        uint4 v2 = *(const uint4*)&ysm[base + 2 * pstr];
        uint4 v3 = *(const uint4*)&ysm[base + 3 * pstr];
        const unsigned short* u0 = (const unsigned short*)&v0;
        const unsigned short* u1 = (const unsigned short*)&v1;
        const unsigned short* u2 = (const unsigned short*)&v2;
        const unsigned short* u3 = (const unsigned short*)&v3;
        float o[8];
#pragma unroll
        for (int j = 0; j < 8; ++j)
            o[j] = bu2f(u0[j]) + bu2f(u1[j]) + bu2f(u2[j]) + bu2f(u3[j]);
        *(float4*)&rb[pos * DIN + c]     = make_float4(o[0], o[1], o[2], o[3]);
        *(float4*)&rb[pos * DIN + c + 4] = make_float4(o[4], o[5], o[6], o[7]);
    }
    __syncthreads();
    {
        int pos = t >> 4, part = t & 15;
        float s = 0.f, s2 = 0.f;
        for (int i = 0; i < 12; ++i) {
            float v = rb[pos * DIN + part * 12 + i];
            s += v; s2 += v * v;
        }
        ps[pos * 16 + part] = s; pq[pos * 16 + part] = s2;
    }
    __syncthreads();
    if (t < 16) {
        float s = 0.f, s2 = 0.f;
        for (int i = 0; i < 16; ++i) { s += ps[t * 16 + i]; s2 += pq[t * 16 + i]; }
        float m = s * (1.f / DIN);
        float v = s2 * (1.f / DIN) - m * m;
        mrow[t] = m; srow[t] = rsqrtf(v + 1e-5f);
    }
    __syncthreads();
    for (int q8 = t; q8 < 16 * DIN / 8; q8 += 256) {
        int pos = q8 / 24, c = (q8 - pos * 24) * 8;
        int P = P0 + pos;
        float m = mrow[pos], sr = srow[pos];
        uint4 zv4 = *(const uint4*)&z[(size_t)P * DIN + c];
        const unsigned short* zu = (const unsigned short*)&zv4;
        unsigned short ou[8];
#pragma unroll
        for (int j = 0; j < 8; ++j) {
            float v = (rb[pos * DIN + c + j] - m) * sr * onw[c + j] + onb[c + j];
            float zv = bu2f(zu[j]);
            v *= zv * sigm(zv);
            ou[j] = f2bu(v);
        }
        *(uint4*)&ymod[(size_t)P * DIN + c] = *(const uint4*)ou;
    }
}

extern "C" void kernel_launch(void* const* d_in, const int* in_sizes, int n_in,
                              void* d_out, int out_size, void* d_ws, size_t ws_size,
                              hipStream_t stream) {
    const float* x      = (const float*)d_in[0];
    const float* ln1w   = (const float*)d_in[1];
    const float* ln1b   = (const float*)d_in[2];
    const float* inpW   = (const float*)d_in[3];
    const float* convW  = (const float*)d_in[4];
    const float* convB  = (const float*)d_in[5];
    const float* xprojW = (const float*)d_in[6];
    const float* dtW    = (const float*)d_in[7];
    const float* dtB    = (const float*)d_in[8];
    const float* Alog   = (const float*)d_in[9];
    const float* Dsp    = (const float*)d_in[10];
    const float* onw    = (const float*)d_in[11];
    const float* onb    = (const float*)d_in[12];
    const float* outW   = (const float*)d_in[13];
    const float* ln2w   = (const float*)d_in[14];
    const float* ln2b   = (const float*)d_in[15];
    const float* fc1W   = (const float*)d_in[16];
    const float* fc1b   = (const float*)d_in[17];
    const float* fc2W   = (const float*)d_in[18];
    const float* fc2b   = (const float*)d_in[19];
    float* out = (float*)d_out;

    char* ws = (char*)d_ws;
    // layout (byte offsets; lifetimes verified stage-by-stage):
    unsigned short* z_us    = (unsigned short*)(ws + 0);          // [G1..k65]   9,633,792
    bf16*  z_bf             = (bf16*)z_us;
    bf16*  xconv_bf         = (bf16*)(ws + 9633792);              // [k2..k4]    9,633,792
    float* proj_f           = (float*)(ws + 19267584);            // [G2..k6]   15,253,504
    bf16*  ymod_bf          = (bf16*)(ws + 19267584);             // [k65..G3]  alias proj
    float* tsum_f           = (float*)(ws + 34521088);            // [k4..k5]    2,752,512
    unsigned short* xcpre_us= (unsigned short*)(ws + 39337984);   // [G1..k2]    9,633,792
    float* hloc_f           = (float*)(ws + 39337984);            // [k4..k6]   44,040,192 (alias dead xcpre)
    float* hin_f            = hloc_f;                             // k5 r-b-w alias
    float* y1_f             = (float*)(ws + 39337984);            // [G3..G5]   alias dead hloc
    bf16*  ysm_bf           = (bf16*)(ws + 83378176);             // [k4..k65]  38,535,168
    unsigned short* hmlp_us = (unsigned short*)(ws + 83378176);   // [G4..G5]   alias dead ysm
    float* a2g_f            = (float*)(ws + 121913344);           // [k0..k6]   49,152
    unsigned short* wbf_us  = (unsigned short*)(ws + 121962496);  // [k0w..G5]  316,416 (end 122,278,912)

    k0_pre<<<48, 256, 0, stream>>>(Alog, a2g_f);
    k0w<<<618, 256, 0, stream>>>(inpW, xprojW, outW, fc1W, fc2W, wbf_us);
    gemm_mfma<384, 96, 0, true><<<dim3(196, 6), 256, 0, stream>>>(
        x, wbf_us + 0, nullptr, nullptr, ln1w, ln1b, xcpre_us, z_us);
    k2_conv<<<4704, 256, 0, stream>>>(xcpre_us, convW, convB,
                                      (unsigned short*)xconv_bf);
    gemm_mfma<152, 192, 1, false><<<dim3(196, 3), 256, 0, stream>>>(
        xconv_bf, wbf_us + 36864, nullptr, nullptr, nullptr, nullptr,
        proj_f, nullptr);
    k4_scan1y<<<1792, 192, 0, stream>>>(xconv_bf, proj_f, dtW, dtB, a2g_f, Dsp,
                                        hloc_f, tsum_f, ysm_bf);
    k5_carry<<<384, 256, 0, stream>>>(hloc_f, tsum_f, a2g_f, hin_f);
    k6_corr<<<1792, 192, 0, stream>>>(proj_f, dtW, dtB, a2g_f, hin_f, ysm_bf);
    k65_merge<<<1568, 256, 0, stream>>>(ysm_bf, z_bf, onw, onb, ymod_bf);
    gemm_mfma<96, 192, 2, false><<<dim3(196, 2), 256, 0, stream>>>(
        ymod_bf, wbf_us + 66048, nullptr, x, nullptr, nullptr, y1_f, nullptr);
    gemm_mfma<384, 96, 3, true><<<dim3(196, 6), 256, 0, stream>>>(
        y1_f, wbf_us + 84480, fc1b, nullptr, ln2w, ln2b, hmlp_us, nullptr);
    gemm_mfma<96, 384, 4, false><<<dim3(196, 2), 256, 0, stream>>>(
        hmlp_us, wbf_us + 121344, fc2b, y1_f, nullptr, nullptr, out, nullptr);
}

// Round 9
// 358.507 us; speedup vs baseline: 1.2558x; 1.2558x over previous
//
#include <hip/hip_runtime.h>
#include <hip/hip_bf16.h>

typedef __hip_bfloat16 bf16;
typedef short bf16x8 __attribute__((ext_vector_type(8)));
typedef float f32x4 __attribute__((ext_vector_type(4)));

#define BBATCH 8
#define HHH 56
#define WWW 56
#define CCH 96          // C
#define DIN 192         // D
#define NST 16          // N
#define KDIR 4          // K
#define RDT 6           // R
#define LLEN 3136       // H*W
#define BLTOT 25088     // B*L
#define SSEG 112        // segments (112 * 28 = 3136)
#define SEGL 28         // L / SSEG
#define PJC 38          // R + 2N
#define PJW 152         // K * PJC
#define PJS 40          // padded LDS row stride (16B aligned)
#define PJS1 24         // pass-1 padded row stride (r+B only)
#define MLPH 384

// native exp2/log2 (v_exp_f32 / v_log_f32) with safe fallbacks
#if defined(__has_builtin)
#if __has_builtin(__builtin_amdgcn_exp2f)
#define EXP2F(x) __builtin_amdgcn_exp2f(x)
#endif
#if __has_builtin(__builtin_amdgcn_logf)
#define LOG2F_(x) __builtin_amdgcn_logf(x)
#endif
#endif
#ifndef EXP2F
#define EXP2F(x) __expf((x) * 0.69314718056f)
#endif
#ifndef LOG2F_
#define LOG2F_(x) (__logf(x) * 1.44269504f)
#endif
#define LOG2E 1.44269504f

// packed fp32 (VOP3P, gfx90a+/gfx950). NOTE: all-VGPR operands only —
// an SGPR source on VOP3P is 32-bit and broadcast to BOTH packed
// components, which silently corrupts per-component math.
__device__ __forceinline__ float2 pk_mul(float2 a, float2 b) {
    float2 d;
    asm("v_pk_mul_f32 %0, %1, %2" : "=v"(d) : "v"(a), "v"(b));
    return d;
}
__device__ __forceinline__ float2 pk_fma(float2 a, float2 b, float2 c) {
    float2 d;
    asm("v_pk_fma_f32 %0, %1, %2, %3" : "=v"(d) : "v"(a), "v"(b), "v"(c));
    return d;
}

__device__ __forceinline__ float b2f(bf16 v) { return __bfloat162float(v); }
__device__ __forceinline__ bf16  f2b(float v) { return __float2bfloat16(v); }
__device__ __forceinline__ unsigned short f2bu(float f) {
    union { bf16 h; unsigned short u; } c; c.h = __float2bfloat16(f); return c.u;
}
__device__ __forceinline__ float bu2f(unsigned short u) {
    union { unsigned short u; bf16 h; } c; c.u = u; return __bfloat162float(c.h);
}
__device__ __forceinline__ float sigm(float x) { return 1.f / (1.f + __expf(-x)); }
__device__ __forceinline__ float softplusf(float x) {
    float t = EXP2F(-fabsf(x) * LOG2E);
    return fmaxf(x, 0.f) + 0.69314718f * LOG2F_(1.f + t);
}
__device__ __forceinline__ float geluf(float v) {
    float u = 0.7978845608028654f * (v + 0.044715f * v * v * v);
    float ey = __expf(2.f * u);
    float th = 1.f - 2.f / (ey + 1.f);
    return 0.5f * v * (1.f + th);
}

// scan-step l -> spatial position (row-major h*56+w) for direction k
__device__ __forceinline__ int pos_map(int k, int l) {
    if (k & 2) l = LLEN - 1 - l;
    if (k & 1) { int q = l / WWW; int r = l - q * WWW; return r * WWW + q; }
    return l;
}

// ---- K0: precompute a2[k][d][n] = -exp(Alog)*log2e --------------------------
__global__ __launch_bounds__(256) void k0_pre(
    const float* __restrict__ Alog, float* __restrict__ a2g) {
    int i = blockIdx.x * 256 + threadIdx.x;   // over K*D*N = 12288
    a2g[i] = -__expf(Alog[i]) * LOG2E;
}

// ---- K0w: pre-convert the 5 GEMM weight matrices to bf16 --------------------
// layout in wbf: inpW@0(36864) xprojW@36864(29184) outW@66048(18432)
//               fc1W@84480(36864) fc2W@121344(36864)  total 158208
__global__ __launch_bounds__(256) void k0w(
    const float* __restrict__ w1, const float* __restrict__ w2,
    const float* __restrict__ w3, const float* __restrict__ w4,
    const float* __restrict__ w5, unsigned short* __restrict__ o) {
    int i = blockIdx.x * 256 + threadIdx.x;
    float v;
    if (i < 36864)       v = w1[i];
    else if (i < 66048)  v = w2[i - 36864];
    else if (i < 84480)  v = w3[i - 66048];
    else if (i < 121344) v = w4[i - 84480];
    else                 v = w5[i - 121344];
    o[i] = f2bu(v);
}

// ---- Unified MFMA GEMM: C[M=25088][N] = A[M][K] . Wb[N][K]^T(bf16) ---------
// block: 4 waves, each wave a 32-row M-strip, 2x4 frags -> 128M x 64N tile.
// LNIN: A is f32 (K=96) with LayerNorm fused during staging.
// EPI: 0=split xc/z  1=proj f32  2=+res f32  3=gelu(+bias) bf16  4=+bias+res f32
template<int N, int K, int EPI, bool LNIN>
__global__ __launch_bounds__(256) void gemm_mfma(
    const void* __restrict__ Xv, const unsigned short* __restrict__ Wb,
    const float* __restrict__ bias, const float* __restrict__ res,
    const float* __restrict__ lnw, const float* __restrict__ lnb,
    void* __restrict__ out0v, void* __restrict__ out1v) {
    __shared__ unsigned short a_sh[128 * 40];
    __shared__ unsigned short b_sh[64 * 40];
    __shared__ float mrow[128], rrow[128];
    __shared__ float lnw_sh[96], lnb_sh[96];
    const int t = threadIdx.x;
    const int P0 = blockIdx.x * 128;
    const int N0 = blockIdx.y * 64;
    const int w = t >> 6, lane = t & 63, q = lane >> 4, nl = lane & 15;
    if constexpr (LNIN) {
        // row stats: 2 threads per row, 48 elems each
        const float* Xf = (const float*)Xv;
        const float* xr = Xf + (size_t)(P0 + (t >> 1)) * 96 + (t & 1) * 48;
        float s = 0.f, s2 = 0.f;
#pragma unroll
        for (int i = 0; i < 12; ++i) {
            float4 v = *(const float4*)&xr[i * 4];
            s += v.x + v.y + v.z + v.w;
            s2 += v.x * v.x + v.y * v.y + v.z * v.z + v.w * v.w;
        }
        s += __shfl_xor(s, 1); s2 += __shfl_xor(s2, 1);
        if ((t & 1) == 0) {
            float m = s * (1.f / 96.f);
            float var = s2 * (1.f / 96.f) - m * m;
            mrow[t >> 1] = m; rrow[t >> 1] = rsqrtf(var + 1e-5f);
        }
        if (t < 96) { lnw_sh[t] = lnw[t]; lnb_sh[t] = lnb[t]; }
    }
    f32x4 acc[2][4];
#pragma unroll
    for (int i = 0; i < 2; ++i)
#pragma unroll
        for (int j = 0; j < 4; ++j)
            acc[i][j] = (f32x4){0.f, 0.f, 0.f, 0.f};
    for (int k0 = 0; k0 < K; k0 += 32) {
        __syncthreads();
        // stage A: 128 rows x 32 k
#pragma unroll
        for (int it = 0; it < 2; ++it) {
            int idx = t + it * 256;
            int pr = idx >> 2, kq = idx & 3;
            if constexpr (LNIN) {
                const float* Xf = (const float*)Xv;
                const float* src = &Xf[(size_t)(P0 + pr) * K + k0 + kq * 8];
                float m = mrow[pr], r = rrow[pr];
                float4 v0 = *(const float4*)src;
                float4 v1 = *(const float4*)(src + 4);
                int c0 = k0 + kq * 8;
                ushort4 u0, u1;
                u0.x = f2bu((v0.x - m) * r * lnw_sh[c0+0] + lnb_sh[c0+0]);
                u0.y = f2bu((v0.y - m) * r * lnw_sh[c0+1] + lnb_sh[c0+1]);
                u0.z = f2bu((v0.z - m) * r * lnw_sh[c0+2] + lnb_sh[c0+2]);
                u0.w = f2bu((v0.w - m) * r * lnw_sh[c0+3] + lnb_sh[c0+3]);
                u1.x = f2bu((v1.x - m) * r * lnw_sh[c0+4] + lnb_sh[c0+4]);
                u1.y = f2bu((v1.y - m) * r * lnw_sh[c0+5] + lnb_sh[c0+5]);
                u1.z = f2bu((v1.z - m) * r * lnw_sh[c0+6] + lnb_sh[c0+6]);
                u1.w = f2bu((v1.w - m) * r * lnw_sh[c0+7] + lnb_sh[c0+7]);
                *(ushort4*)&a_sh[pr * 40 + kq * 8] = u0;
                *(ushort4*)&a_sh[pr * 40 + kq * 8 + 4] = u1;
            } else {
                const unsigned short* X = (const unsigned short*)Xv;
                uint4 v = *(const uint4*)&X[(size_t)(P0 + pr) * K + k0 + kq * 8];
                *(uint4*)&a_sh[pr * 40 + kq * 8] = v;
            }
        }
        // stage B: 64 rows x 32 k (bf16 pass-through, 1 uint4/thread)
        {
            int nr = t >> 2, kq = t & 3;
            int ng = N0 + nr; if (ng > N - 1) ng = N - 1;
            uint4 v = *(const uint4*)&Wb[(size_t)ng * K + k0 + kq * 8];
            *(uint4*)&b_sh[nr * 40 + kq * 8] = v;
        }
        __syncthreads();
        bf16x8 af[2], bfr[4];
#pragma unroll
        for (int mf = 0; mf < 2; ++mf)
            af[mf] = *(const bf16x8*)&a_sh[(w * 32 + mf * 16 + nl) * 40 + q * 8];
#pragma unroll
        for (int nf = 0; nf < 4; ++nf)
            bfr[nf] = *(const bf16x8*)&b_sh[(nf * 16 + nl) * 40 + q * 8];
#pragma unroll
        for (int mf = 0; mf < 2; ++mf)
#pragma unroll
            for (int nf = 0; nf < 4; ++nf)
                acc[mf][nf] = __builtin_amdgcn_mfma_f32_16x16x32_bf16(
                    af[mf], bfr[nf], acc[mf][nf], 0, 0, 0);
    }
#pragma unroll
    for (int mf = 0; mf < 2; ++mf) {
#pragma unroll
        for (int nf = 0; nf < 4; ++nf) {
#pragma unroll
            for (int r = 0; r < 4; ++r) {
                float v = acc[mf][nf][r];
                size_t pos = (size_t)P0 + w * 32 + mf * 16 + q * 4 + r;
                int n = N0 + nf * 16 + nl;
                if constexpr (EPI == 0) {
                    unsigned short* xc = (unsigned short*)out0v;
                    unsigned short* zz = (unsigned short*)out1v;
                    if (n < 192) xc[pos * 192 + n] = f2bu(v);
                    else         zz[pos * 192 + (n - 192)] = f2bu(v);
                } else if constexpr (EPI == 1) {
                    if (n < 152) ((float*)out0v)[pos * 152 + n] = v;
                } else if constexpr (EPI == 2) {
                    if (n < 96) ((float*)out0v)[pos * 96 + n] = res[pos * 96 + n] + v;
                } else if constexpr (EPI == 3) {
                    ((unsigned short*)out0v)[pos * 384 + n] = f2bu(geluf(v + bias[n]));
                } else {
                    if (n < 96) ((float*)out0v)[pos * 96 + n] =
                        res[pos * 96 + n] + bias[n] + v;
                }
            }
        }
    }
}

// ---- K2: depthwise 3x3 conv + bias + silu, 4 channels/thread ---------------
__global__ __launch_bounds__(256) void k2_conv(
    const unsigned short* __restrict__ xcpre, const float* __restrict__ cw,
    const float* __restrict__ cb, unsigned short* __restrict__ xconv) {
    int idx = blockIdx.x * 256 + threadIdx.x;
    int dd = idx % 48;
    int P = idx / 48;
    int d0 = dd * 4;
    int b = P / LLEN, l = P - b * LLEN;
    int h = l / WWW, w = l - h * WWW;
    float acc0 = cb[d0], acc1 = cb[d0 + 1], acc2 = cb[d0 + 2], acc3 = cb[d0 + 3];
#pragma unroll
    for (int i = 0; i < 3; ++i) {
        int hh = h + i - 1;
        if (hh < 0 || hh >= HHH) continue;
#pragma unroll
        for (int j = 0; j < 3; ++j) {
            int ww = w + j - 1;
            if (ww < 0 || ww >= WWW) continue;
            ushort4 xv = *(const ushort4*)&xcpre[
                ((size_t)(b * LLEN + hh * WWW + ww)) * DIN + d0];
            acc0 = fmaf(bu2f(xv.x), cw[(d0 + 0) * 9 + i * 3 + j], acc0);
            acc1 = fmaf(bu2f(xv.y), cw[(d0 + 1) * 9 + i * 3 + j], acc1);
            acc2 = fmaf(bu2f(xv.z), cw[(d0 + 2) * 9 + i * 3 + j], acc2);
            acc3 = fmaf(bu2f(xv.w), cw[(d0 + 3) * 9 + i * 3 + j], acc3);
        }
    }
    acc0 = acc0 * sigm(acc0); acc1 = acc1 * sigm(acc1);
    acc2 = acc2 * sigm(acc2); acc3 = acc3 * sigm(acc3);
    ushort4 o;
    o.x = f2bu(acc0); o.y = f2bu(acc1); o.z = f2bu(acc2); o.w = f2bu(acc3);
    *(ushort4*)&xconv[(size_t)P * DIN + d0] = o;
}

// ---- K4: scan pass 1 — one segment per block, packed-fp32, fp32 h-out ------
__global__ __launch_bounds__(192) void k4_scan1(
    const bf16* __restrict__ xconv, const float* __restrict__ proj,
    const float* __restrict__ dtw, const float* __restrict__ dtb,
    const float* __restrict__ a2g, float* __restrict__ hloc,
    float* __restrict__ tsum) {
    __shared__ float pl[SEGL * PJS1];
    __shared__ int posl[SEGL];
    const int bid = blockIdx.x;              // 3584 = (b*4+k)*112 + s
    const int s = bid % SSEG;
    const int bk = bid / SSEG;
    const int k = bk & 3, b = bk >> 2;
    const int d = threadIdx.x;
    const int l0 = s * SEGL;
    for (int q = d; q < SEGL * 22; q += 192) {
        int st = q / 22, c = q - st * 22;
        int p = pos_map(k, l0 + st);
        int ofs = (c < 6) ? c : c + 2;
        pl[st * PJS1 + ofs] = proj[(size_t)(b * LLEN + p) * PJW + k * PJC + c];
    }
    if (d < SEGL) posl[d] = pos_map(k, l0 + d) * DIN;
    float w6[RDT];
#pragma unroll
    for (int r = 0; r < RDT; ++r) w6[r] = dtw[(k * DIN + d) * RDT + r];
    const float bias = dtb[k * DIN + d];
    float2 a2[8];
#pragma unroll
    for (int j = 0; j < 8; ++j)
        a2[j] = *(const float2*)&a2g[(k * DIN + d) * NST + 2 * j];
    float2 h2[8];
#pragma unroll
    for (int j = 0; j < 8; ++j) h2[j] = make_float2(0.f, 0.f);
    float T = 0.f;
    __syncthreads();
    const bf16* xg = xconv + (size_t)b * LLEN * DIN + d;
    for (int bt = 0; bt < 4; ++bt) {
        int off7[7]; float xv7[7];
#pragma unroll
        for (int i = 0; i < 7; ++i) off7[i] = posl[bt * 7 + i];
#pragma unroll
        for (int i = 0; i < 7; ++i) xv7[i] = b2f(xg[off7[i]]);
#pragma unroll
        for (int i = 0; i < 7; ++i) {
            const float* rowf = &pl[(bt * 7 + i) * PJS1];
            float4 g0 = *(const float4*)(rowf);
            float2 g1 = *(const float2*)(rowf + 4);
            float dtv = bias;
            dtv = fmaf(g0.x, w6[0], dtv); dtv = fmaf(g0.y, w6[1], dtv);
            dtv = fmaf(g0.z, w6[2], dtv); dtv = fmaf(g0.w, w6[3], dtv);
            dtv = fmaf(g1.x, w6[4], dtv); dtv = fmaf(g1.y, w6[5], dtv);
            dtv = softplusf(dtv);
            T += dtv;
            float2 dt2 = make_float2(dtv, dtv);
            float2 u2 = make_float2(dtv * xv7[i], dtv * xv7[i]);
#pragma unroll
            for (int g = 0; g < 4; ++g) {
                float4 Bv = *(const float4*)(rowf + 8 + 4 * g);
                float2 Blo = make_float2(Bv.x, Bv.y);
                float2 Bhi = make_float2(Bv.z, Bv.w);
                float2 alo = pk_mul(dt2, a2[2 * g]);
                float2 ahi = pk_mul(dt2, a2[2 * g + 1]);
                float2 elo, ehi;
                elo.x = EXP2F(alo.x); elo.y = EXP2F(alo.y);
                ehi.x = EXP2F(ahi.x); ehi.y = EXP2F(ahi.y);
                h2[2 * g]     = pk_fma(h2[2 * g],     elo, pk_mul(u2, Blo));
                h2[2 * g + 1] = pk_fma(h2[2 * g + 1], ehi, pk_mul(u2, Bhi));
            }
        }
    }
    size_t base = ((size_t)bid * DIN + d) * NST;
#pragma unroll
    for (int j = 0; j < 8; ++j) *(float2*)&hloc[base + 2 * j] = h2[j];
    tsum[bid * DIN + d] = T;
}

// ---- K5: exact segment carries, 8-segment batched loads --------------------
// hin aliases hloc (read-before-write). Batching: all 8 loads of a batch
// issue before any of its 8 stores (addresses strictly increasing, each
// address read once then written once with the pre-update carry) — bitwise
// identical semantics to the serial loop, but 8-deep memory-level
// parallelism instead of one latency-serialized load per iteration.
__global__ __launch_bounds__(256) void k5_carry(
    const float* hloc, const float* __restrict__ tsum,
    const float* __restrict__ a2g, float* hin) {
    int g = blockIdx.x * 256 + threadIdx.x;   // over B*K*D*N
    int n = g & 15;
    int dk = g >> 4;
    int d = dk % DIN;
    int bk = dk / DIN;                        // b*4 + k
    int k = bk & 3;
    float a2 = a2g[(k * DIN + d) * NST + n];
    float Hc = 0.f;
    for (int s0 = 0; s0 < SSEG; s0 += 8) {
        float hl[8], Tv[8];
#pragma unroll
        for (int j = 0; j < 8; ++j) {
            int bid = bk * SSEG + s0 + j;
            size_t idx = ((size_t)bid * DIN + d) * NST + n;
            hl[j] = hloc[idx];
            Tv[j] = tsum[bid * DIN + d];
        }
        float dec[8];
#pragma unroll
        for (int j = 0; j < 8; ++j) dec[j] = EXP2F(a2 * Tv[j]);
        float out[8];
#pragma unroll
        for (int j = 0; j < 8; ++j) {
            out[j] = Hc;
            Hc = fmaf(dec[j], Hc, hl[j]);
        }
#pragma unroll
        for (int j = 0; j < 8; ++j) {
            int bid = bk * SSEG + s0 + j;
            size_t idx = ((size_t)bid * DIN + d) * NST + n;
            hin[idx] = out[j];
        }
    }
}

// ---- K6: scan pass 2 — one segment per block, packed-fp32, fp32 h-in -------
__global__ __launch_bounds__(192) void k6_scan2(
    const bf16* __restrict__ xconv, const float* __restrict__ proj,
    const float* __restrict__ dtw, const float* __restrict__ dtb,
    const float* __restrict__ a2g, const float* __restrict__ Dsp,
    const float* __restrict__ hin, bf16* __restrict__ ysm) {
    __shared__ float pl[SEGL * PJS];
    __shared__ int posl[SEGL];
    const int bid = blockIdx.x;
    const int s = bid % SSEG;
    const int bk = bid / SSEG;
    const int k = bk & 3, b = bk >> 2;
    const int d = threadIdx.x;
    const int l0 = s * SEGL;
    for (int q = d; q < SEGL * PJC; q += 192) {
        int st = q / PJC, c = q - st * PJC;
        int p = pos_map(k, l0 + st);
        int ofs = (c < 6) ? c : c + 2;
        pl[st * PJS + ofs] = proj[(size_t)(b * LLEN + p) * PJW + k * PJC + c];
    }
    if (d < SEGL) posl[d] = pos_map(k, l0 + d) * DIN;
    float w6[RDT];
#pragma unroll
    for (int r = 0; r < RDT; ++r) w6[r] = dtw[(k * DIN + d) * RDT + r];
    const float bias = dtb[k * DIN + d];
    const float dsv = Dsp[k * DIN + d];
    float2 a2[8];
#pragma unroll
    for (int j = 0; j < 8; ++j)
        a2[j] = *(const float2*)&a2g[(k * DIN + d) * NST + 2 * j];
    float2 h2[8];
    size_t hbase = ((size_t)bid * DIN + d) * NST;
#pragma unroll
    for (int j = 0; j < 8; ++j) h2[j] = *(const float2*)&hin[hbase + 2 * j];
    __syncthreads();
    const bf16* xg = xconv + (size_t)b * LLEN * DIN + d;
    bf16* ysg = ysm + ((size_t)bk * LLEN) * DIN + d;
    for (int bt = 0; bt < 4; ++bt) {
        int off7[7]; float xv7[7];
#pragma unroll
        for (int i = 0; i < 7; ++i) off7[i] = posl[bt * 7 + i];
#pragma unroll
        for (int i = 0; i < 7; ++i) xv7[i] = b2f(xg[off7[i]]);
#pragma unroll
        for (int i = 0; i < 7; ++i) {
            const float* rowf = &pl[(bt * 7 + i) * PJS];
            float4 g0 = *(const float4*)(rowf);
            float2 g1 = *(const float2*)(rowf + 4);
            float dtv = bias;
            dtv = fmaf(g0.x, w6[0], dtv); dtv = fmaf(g0.y, w6[1], dtv);
            dtv = fmaf(g0.z, w6[2], dtv); dtv = fmaf(g0.w, w6[3], dtv);
            dtv = fmaf(g1.x, w6[4], dtv); dtv = fmaf(g1.y, w6[5], dtv);
            dtv = softplusf(dtv);
            float2 dt2 = make_float2(dtv, dtv);
            float2 u2 = make_float2(dtv * xv7[i], dtv * xv7[i]);
            float2 yac0 = make_float2(0.f, 0.f), yac1 = make_float2(0.f, 0.f);
#pragma unroll
            for (int g = 0; g < 4; ++g) {
                float4 Bv = *(const float4*)(rowf + 8 + 4 * g);
                float4 Cv = *(const float4*)(rowf + 24 + 4 * g);
                float2 Blo = make_float2(Bv.x, Bv.y);
                float2 Bhi = make_float2(Bv.z, Bv.w);
                float2 Clo = make_float2(Cv.x, Cv.y);
                float2 Chi = make_float2(Cv.z, Cv.w);
                float2 alo = pk_mul(dt2, a2[2 * g]);
                float2 ahi = pk_mul(dt2, a2[2 * g + 1]);
                float2 elo, ehi;
                elo.x = EXP2F(alo.x); elo.y = EXP2F(alo.y);
                ehi.x = EXP2F(ahi.x); ehi.y = EXP2F(ahi.y);
                h2[2 * g]     = pk_fma(h2[2 * g],     elo, pk_mul(u2, Blo));
                h2[2 * g + 1] = pk_fma(h2[2 * g + 1], ehi, pk_mul(u2, Bhi));
                yac0 = pk_fma(h2[2 * g],     Clo, yac0);
                yac1 = pk_fma(h2[2 * g + 1], Chi, yac1);
            }
            float y = (yac0.x + yac0.y) + (yac1.x + yac1.y);
            ysg[off7[i]] = f2b(fmaf(dsv, xv7[i], y));
        }
    }
}

// ---- K6.5: merge 4 planes + out_norm LN + *silu(z), 8-wide bf16 vecio ------
__global__ __launch_bounds__(256) void k65_merge(
    const bf16* __restrict__ ysm, const bf16* __restrict__ z,
    const float* __restrict__ onw, const float* __restrict__ onb,
    bf16* __restrict__ ymod) {
    __shared__ float rb[16 * DIN];
    __shared__ float ps[256], pq[256];
    __shared__ float mrow[16], srow[16];
    const int t = threadIdx.x;
    const int P0 = blockIdx.x * 16;
    // fill: 384 groups of 8 channels (uint4 = 8 bf16 per plane)
    for (int q8 = t; q8 < 16 * DIN / 8; q8 += 256) {
        int pos = q8 / 24, c = (q8 - pos * 24) * 8;
        int P = P0 + pos;
        int b = P / LLEN, l = P - b * LLEN;
        size_t base = ((size_t)(b * KDIR) * LLEN + l) * DIN + c;
        size_t pstr = (size_t)LLEN * DIN;
        uint4 v0 = *(const uint4*)&ysm[base];
        uint4 v1 = *(const uint4*)&ysm[base + pstr];
        uint4 v2 = *(const uint4*)&ysm[base + 2 * pstr];
        uint4 v3 = *(const uint4*)&ysm[base + 3 * pstr];
        const unsigned short* u0 = (const unsigned short*)&v0;
        const unsigned short* u1 = (const unsigned short*)&v1;
        const unsigned short* u2 = (const unsigned short*)&v2;
        const unsigned short* u3 = (const unsigned short*)&v3;
        float o[8];
#pragma unroll
        for (int j = 0; j < 8; ++j)
            o[j] = bu2f(u0[j]) + bu2f(u1[j]) + bu2f(u2[j]) + bu2f(u3[j]);
        *(float4*)&rb[pos * DIN + c]     = make_float4(o[0], o[1], o[2], o[3]);
        *(float4*)&rb[pos * DIN + c + 4] = make_float4(o[4], o[5], o[6], o[7]);
    }
    __syncthreads();
    {
        int pos = t >> 4, part = t & 15;
        float s = 0.f, s2 = 0.f;
        for (int i = 0; i < 12; ++i) {
            float v = rb[pos * DIN + part * 12 + i];
            s += v; s2 += v * v;
        }
        ps[pos * 16 + part] = s; pq[pos * 16 + part] = s2;
    }
    __syncthreads();
    if (t < 16) {
        float s = 0.f, s2 = 0.f;
        for (int i = 0; i < 16; ++i) { s += ps[t * 16 + i]; s2 += pq[t * 16 + i]; }
        float m = s * (1.f / DIN);
        float v = s2 * (1.f / DIN) - m * m;
        mrow[t] = m; srow[t] = rsqrtf(v + 1e-5f);
    }
    __syncthreads();
    for (int q8 = t; q8 < 16 * DIN / 8; q8 += 256) {
        int pos = q8 / 24, c = (q8 - pos * 24) * 8;
        int P = P0 + pos;
        float m = mrow[pos], sr = srow[pos];
        uint4 zv4 = *(const uint4*)&z[(size_t)P * DIN + c];
        const unsigned short* zu = (const unsigned short*)&zv4;
        unsigned short ou[8];
#pragma unroll
        for (int j = 0; j < 8; ++j) {
            float v = (rb[pos * DIN + c + j] - m) * sr * onw[c + j] + onb[c + j];
            float zv = bu2f(zu[j]);
            v *= zv * sigm(zv);
            ou[j] = f2bu(v);
        }
        *(uint4*)&ymod[(size_t)P * DIN + c] = *(const uint4*)ou;
    }
}

extern "C" void kernel_launch(void* const* d_in, const int* in_sizes, int n_in,
                              void* d_out, int out_size, void* d_ws, size_t ws_size,
                              hipStream_t stream) {
    const float* x      = (const float*)d_in[0];
    const float* ln1w   = (const float*)d_in[1];
    const float* ln1b   = (const float*)d_in[2];
    const float* inpW   = (const float*)d_in[3];
    const float* convW  = (const float*)d_in[4];
    const float* convB  = (const float*)d_in[5];
    const float* xprojW = (const float*)d_in[6];
    const float* dtW    = (const float*)d_in[7];
    const float* dtB    = (const float*)d_in[8];
    const float* Alog   = (const float*)d_in[9];
    const float* Dsp    = (const float*)d_in[10];
    const float* onw    = (const float*)d_in[11];
    const float* onb    = (const float*)d_in[12];
    const float* outW   = (const float*)d_in[13];
    const float* ln2w   = (const float*)d_in[14];
    const float* ln2b   = (const float*)d_in[15];
    const float* fc1W   = (const float*)d_in[16];
    const float* fc1b   = (const float*)d_in[17];
    const float* fc2W   = (const float*)d_in[18];
    const float* fc2b   = (const float*)d_in[19];
    float* out = (float*)d_out;

    char* ws = (char*)d_ws;
    // layout (byte offsets; lifetimes verified stage-by-stage):
    unsigned short* z_us    = (unsigned short*)(ws + 0);          // [G1..k65]   9,633,792
    bf16*  z_bf             = (bf16*)z_us;
    bf16*  xconv_bf         = (bf16*)(ws + 9633792);              // [k2..k6]    9,633,792
    float* proj_f           = (float*)(ws + 19267584);            // [G2..k6]   15,253,504
    bf16*  ymod_bf          = (bf16*)(ws + 19267584);             // [k65..G3]  alias proj
    float* tsum_f           = (float*)(ws + 34521088);            // [k4..k5]    2,752,512
    unsigned short* xcpre_us= (unsigned short*)(ws + 39337984);   // [G1..k2]    9,633,792
    float* hloc_f           = (float*)(ws + 39337984);            // [k4..k6]   44,040,192 (alias dead xcpre)
    float* hin_f            = hloc_f;                             // k5 r-b-w alias
    float* y1_f             = (float*)(ws + 39337984);            // [G3..G5]   alias dead hloc
    bf16*  ysm_bf           = (bf16*)(ws + 83378176);             // [k6..k65]  38,535,168
    unsigned short* hmlp_us = (unsigned short*)(ws + 83378176);   // [G4..G5]   alias dead ysm
    float* a2g_f            = (float*)(ws + 121913344);           // [k0..k6]   49,152
    unsigned short* wbf_us  = (unsigned short*)(ws + 121962496);  // [k0w..G5]  316,416 (end 122,278,912)

    k0_pre<<<48, 256, 0, stream>>>(Alog, a2g_f);
    k0w<<<618, 256, 0, stream>>>(inpW, xprojW, outW, fc1W, fc2W, wbf_us);
    gemm_mfma<384, 96, 0, true><<<dim3(196, 6), 256, 0, stream>>>(
        x, wbf_us + 0, nullptr, nullptr, ln1w, ln1b, xcpre_us, z_us);
    k2_conv<<<4704, 256, 0, stream>>>(xcpre_us, convW, convB,
                                      (unsigned short*)xconv_bf);
    gemm_mfma<152, 192, 1, false><<<dim3(196, 3), 256, 0, stream>>>(
        xconv_bf, wbf_us + 36864, nullptr, nullptr, nullptr, nullptr,
        proj_f, nullptr);
    k4_scan1<<<3584, 192, 0, stream>>>(xconv_bf, proj_f, dtW, dtB, a2g_f,
                                       hloc_f, tsum_f);
    k5_carry<<<384, 256, 0, stream>>>(hloc_f, tsum_f, a2g_f, hin_f);
    k6_scan2<<<3584, 192, 0, stream>>>(xconv_bf, proj_f, dtW, dtB, a2g_f, Dsp,
                                       hin_f, ysm_bf);
    k65_merge<<<1568, 256, 0, stream>>>(ysm_bf, z_bf, onw, onb, ymod_bf);
    gemm_mfma<96, 192, 2, false><<<dim3(196, 2), 256, 0, stream>>>(
        ymod_bf, wbf_us + 66048, nullptr, x, nullptr, nullptr, y1_f, nullptr);
    gemm_mfma<384, 96, 3, true><<<dim3(196, 6), 256, 0, stream>>>(
        y1_f, wbf_us + 84480, fc1b, nullptr, ln2w, ln2b, hmlp_us, nullptr);
    gemm_mfma<96, 384, 4, false><<<dim3(196, 2), 256, 0, stream>>>(
        hmlp_us, wbf_us + 121344, fc2b, y1_f, nullptr, nullptr, out, nullptr);
}

// Round 11
// 355.046 us; speedup vs baseline: 1.2681x; 1.0097x over previous
//
#include <hip/hip_runtime.h>
#include <hip/hip_bf16.h>

typedef __hip_bfloat16 bf16;
typedef short bf16x8 __attribute__((ext_vector_type(8)));
typedef float f32x4 __attribute__((ext_vector_type(4)));

#define BBATCH 8
#define HHH 56
#define WWW 56
#define CCH 96          // C
#define DIN 192         // D
#define NST 16          // N
#define KDIR 4          // K
#define RDT 6           // R
#define LLEN 3136       // H*W
#define BLTOT 25088     // B*L
#define SSEG 112        // segments (112 * 28 = 3136)
#define SEGL 28         // L / SSEG
#define PJC 38          // R + 2N
#define PJW 152         // K * PJC
#define PJS 40          // padded LDS row stride (16B aligned)
#define PJS1 24         // pass-1 padded row stride (r+B only)
#define MLPH 384

// native exp2/log2 (v_exp_f32 / v_log_f32) with safe fallbacks
#if defined(__has_builtin)
#if __has_builtin(__builtin_amdgcn_exp2f)
#define EXP2F(x) __builtin_amdgcn_exp2f(x)
#endif
#if __has_builtin(__builtin_amdgcn_logf)
#define LOG2F_(x) __builtin_amdgcn_logf(x)
#endif
#endif
#ifndef EXP2F
#define EXP2F(x) __expf((x) * 0.69314718056f)
#endif
#ifndef LOG2F_
#define LOG2F_(x) (__logf(x) * 1.44269504f)
#endif
#define LOG2E 1.44269504f

// packed fp32 (VOP3P, gfx90a+/gfx950). NOTE: all-VGPR operands only —
// an SGPR source on VOP3P is 32-bit and broadcast to BOTH packed
// components, which silently corrupts per-component math.
__device__ __forceinline__ float2 pk_mul(float2 a, float2 b) {
    float2 d;
    asm("v_pk_mul_f32 %0, %1, %2" : "=v"(d) : "v"(a), "v"(b));
    return d;
}
__device__ __forceinline__ float2 pk_fma(float2 a, float2 b, float2 c) {
    float2 d;
    asm("v_pk_fma_f32 %0, %1, %2, %3" : "=v"(d) : "v"(a), "v"(b), "v"(c));
    return d;
}

__device__ __forceinline__ float b2f(bf16 v) { return __bfloat162float(v); }
__device__ __forceinline__ bf16  f2b(float v) { return __float2bfloat16(v); }
__device__ __forceinline__ unsigned short f2bu(float f) {
    union { bf16 h; unsigned short u; } c; c.h = __float2bfloat16(f); return c.u;
}
__device__ __forceinline__ float bu2f(unsigned short u) {
    union { unsigned short u; bf16 h; } c; c.u = u; return __bfloat162float(c.h);
}
__device__ __forceinline__ float sigm(float x) { return 1.f / (1.f + __expf(-x)); }
__device__ __forceinline__ float softplusf(float x) {
    float t = EXP2F(-fabsf(x) * LOG2E);
    return fmaxf(x, 0.f) + 0.69314718f * LOG2F_(1.f + t);
}
__device__ __forceinline__ float geluf(float v) {
    float u = 0.7978845608028654f * (v + 0.044715f * v * v * v);
    float ey = __expf(2.f * u);
    float th = 1.f - 2.f / (ey + 1.f);
    return 0.5f * v * (1.f + th);
}

// scan-step l -> spatial position (row-major h*56+w) for direction k
__device__ __forceinline__ int pos_map(int k, int l) {
    if (k & 2) l = LLEN - 1 - l;
    if (k & 1) { int q = l / WWW; int r = l - q * WWW; return r * WWW + q; }
    return l;
}

// ---- K0: precompute a2[k][d][n] = -exp(Alog)*log2e --------------------------
__global__ __launch_bounds__(256) void k0_pre(
    const float* __restrict__ Alog, float* __restrict__ a2g) {
    int i = blockIdx.x * 256 + threadIdx.x;   // over K*D*N = 12288
    a2g[i] = -__expf(Alog[i]) * LOG2E;
}

// ---- K0w: pre-convert the 5 GEMM weight matrices to bf16 --------------------
// layout in wbf: inpW@0(36864) xprojW@36864(29184) outW@66048(18432)
//               fc1W@84480(36864) fc2W@121344(36864)  total 158208
__global__ __launch_bounds__(256) void k0w(
    const float* __restrict__ w1, const float* __restrict__ w2,
    const float* __restrict__ w3, const float* __restrict__ w4,
    const float* __restrict__ w5, unsigned short* __restrict__ o) {
    int i = blockIdx.x * 256 + threadIdx.x;
    float v;
    if (i < 36864)       v = w1[i];
    else if (i < 66048)  v = w2[i - 36864];
    else if (i < 84480)  v = w3[i - 66048];
    else if (i < 121344) v = w4[i - 84480];
    else                 v = w5[i - 121344];
    o[i] = f2bu(v);
}

// ---- K1: hoisted LayerNorm -> bf16 (bit-identical to the LNIN staging) -----
// 2 threads per row of 96; same stats reduction and same f2bu rounding point
// as the gemm_mfma LNIN path, computed ONCE instead of once per y-tile.
__global__ __launch_bounds__(256) void k1_ln(
    const float* __restrict__ Xf, const float* __restrict__ lnw,
    const float* __restrict__ lnb, unsigned short* __restrict__ Xbf) {
    const int t = threadIdx.x;
    const int row = blockIdx.x * 128 + (t >> 1);
    const int half = t & 1;
    const float* xr = Xf + (size_t)row * 96 + half * 48;
    float4 v[12];
    float s = 0.f, s2 = 0.f;
#pragma unroll
    for (int i = 0; i < 12; ++i) {
        v[i] = *(const float4*)&xr[i * 4];
        s += v[i].x + v[i].y + v[i].z + v[i].w;
        s2 += v[i].x * v[i].x + v[i].y * v[i].y + v[i].z * v[i].z + v[i].w * v[i].w;
    }
    s += __shfl_xor(s, 1); s2 += __shfl_xor(s2, 1);
    float m = s * (1.f / 96.f);
    float var = s2 * (1.f / 96.f) - m * m;
    float r = rsqrtf(var + 1e-5f);
    unsigned short* orow = Xbf + (size_t)row * 96 + half * 48;
#pragma unroll
    for (int i = 0; i < 12; ++i) {
        int c0 = half * 48 + i * 4;
        float4 w4v = *(const float4*)&lnw[c0];
        float4 b4v = *(const float4*)&lnb[c0];
        ushort4 u;
        u.x = f2bu((v[i].x - m) * r * w4v.x + b4v.x);
        u.y = f2bu((v[i].y - m) * r * w4v.y + b4v.y);
        u.z = f2bu((v[i].z - m) * r * w4v.z + b4v.z);
        u.w = f2bu((v[i].w - m) * r * w4v.w + b4v.w);
        *(ushort4*)&orow[i * 4] = u;
    }
}

// ---- Unified MFMA GEMM: C[M=25088][N] = A[M][K] . Wb[N][K]^T(bf16) ---------
// block: 4 waves, each wave a 32-row M-strip, 2x4 frags -> 128M x 64N tile.
// LNIN: A is f32 (K=96) with LayerNorm fused during staging.
// EPI: 0=split xc/z  1=proj f32  2=+res f32  3=gelu(+bias) bf16  4=+bias+res f32
template<int N, int K, int EPI, bool LNIN>
__global__ __launch_bounds__(256) void gemm_mfma(
    const void* __restrict__ Xv, const unsigned short* __restrict__ Wb,
    const float* __restrict__ bias, const float* __restrict__ res,
    const float* __restrict__ lnw, const float* __restrict__ lnb,
    void* __restrict__ out0v, void* __restrict__ out1v) {
    __shared__ unsigned short a_sh[128 * 40];
    __shared__ unsigned short b_sh[64 * 40];
    __shared__ float mrow[128], rrow[128];
    __shared__ float lnw_sh[96], lnb_sh[96];
    const int t = threadIdx.x;
    const int P0 = blockIdx.x * 128;
    const int N0 = blockIdx.y * 64;
    const int w = t >> 6, lane = t & 63, q = lane >> 4, nl = lane & 15;
    if constexpr (LNIN) {
        // row stats: 2 threads per row, 48 elems each
        const float* Xf = (const float*)Xv;
        const float* xr = Xf + (size_t)(P0 + (t >> 1)) * 96 + (t & 1) * 48;
        float s = 0.f, s2 = 0.f;
#pragma unroll
        for (int i = 0; i < 12; ++i) {
            float4 v = *(const float4*)&xr[i * 4];
            s += v.x + v.y + v.z + v.w;
            s2 += v.x * v.x + v.y * v.y + v.z * v.z + v.w * v.w;
        }
        s += __shfl_xor(s, 1); s2 += __shfl_xor(s2, 1);
        if ((t & 1) == 0) {
            float m = s * (1.f / 96.f);
            float var = s2 * (1.f / 96.f) - m * m;
            mrow[t >> 1] = m; rrow[t >> 1] = rsqrtf(var + 1e-5f);
        }
        if (t < 96) { lnw_sh[t] = lnw[t]; lnb_sh[t] = lnb[t]; }
    }
    f32x4 acc[2][4];
#pragma unroll
    for (int i = 0; i < 2; ++i)
#pragma unroll
        for (int j = 0; j < 4; ++j)
            acc[i][j] = (f32x4){0.f, 0.f, 0.f, 0.f};
    for (int k0 = 0; k0 < K; k0 += 32) {
        __syncthreads();
        // stage A: 128 rows x 32 k
#pragma unroll
        for (int it = 0; it < 2; ++it) {
            int idx = t + it * 256;
            int pr = idx >> 2, kq = idx & 3;
            if constexpr (LNIN) {
                const float* Xf = (const float*)Xv;
                const float* src = &Xf[(size_t)(P0 + pr) * K + k0 + kq * 8];
                float m = mrow[pr], r = rrow[pr];
                float4 v0 = *(const float4*)src;
                float4 v1 = *(const float4*)(src + 4);
                int c0 = k0 + kq * 8;
                ushort4 u0, u1;
                u0.x = f2bu((v0.x - m) * r * lnw_sh[c0+0] + lnb_sh[c0+0]);
                u0.y = f2bu((v0.y - m) * r * lnw_sh[c0+1] + lnb_sh[c0+1]);
                u0.z = f2bu((v0.z - m) * r * lnw_sh[c0+2] + lnb_sh[c0+2]);
                u0.w = f2bu((v0.w - m) * r * lnw_sh[c0+3] + lnb_sh[c0+3]);
                u1.x = f2bu((v1.x - m) * r * lnw_sh[c0+4] + lnb_sh[c0+4]);
                u1.y = f2bu((v1.y - m) * r * lnw_sh[c0+5] + lnb_sh[c0+5]);
                u1.z = f2bu((v1.z - m) * r * lnw_sh[c0+6] + lnb_sh[c0+6]);
                u1.w = f2bu((v1.w - m) * r * lnw_sh[c0+7] + lnb_sh[c0+7]);
                *(ushort4*)&a_sh[pr * 40 + kq * 8] = u0;
                *(ushort4*)&a_sh[pr * 40 + kq * 8 + 4] = u1;
            } else {
                const unsigned short* X = (const unsigned short*)Xv;
                uint4 v = *(const uint4*)&X[(size_t)(P0 + pr) * K + k0 + kq * 8];
                *(uint4*)&a_sh[pr * 40 + kq * 8] = v;
            }
        }
        // stage B: 64 rows x 32 k (bf16 pass-through, 1 uint4/thread)
        {
            int nr = t >> 2, kq = t & 3;
            int ng = N0 + nr; if (ng > N - 1) ng = N - 1;
            uint4 v = *(const uint4*)&Wb[(size_t)ng * K + k0 + kq * 8];
            *(uint4*)&b_sh[nr * 40 + kq * 8] = v;
        }
        __syncthreads();
        bf16x8 af[2], bfr[4];
#pragma unroll
        for (int mf = 0; mf < 2; ++mf)
            af[mf] = *(const bf16x8*)&a_sh[(w * 32 + mf * 16 + nl) * 40 + q * 8];
#pragma unroll
        for (int nf = 0; nf < 4; ++nf)
            bfr[nf] = *(const bf16x8*)&b_sh[(nf * 16 + nl) * 40 + q * 8];
#pragma unroll
        for (int mf = 0; mf < 2; ++mf)
#pragma unroll
            for (int nf = 0; nf < 4; ++nf)
                acc[mf][nf] = __builtin_amdgcn_mfma_f32_16x16x32_bf16(
                    af[mf], bfr[nf], acc[mf][nf], 0, 0, 0);
    }
#pragma unroll
    for (int mf = 0; mf < 2; ++mf) {
#pragma unroll
        for (int nf = 0; nf < 4; ++nf) {
#pragma unroll
            for (int r = 0; r < 4; ++r) {
                float v = acc[mf][nf][r];
                size_t pos = (size_t)P0 + w * 32 + mf * 16 + q * 4 + r;
                int n = N0 + nf * 16 + nl;
                if constexpr (EPI == 0) {
                    unsigned short* xc = (unsigned short*)out0v;
                    unsigned short* zz = (unsigned short*)out1v;
                    if (n < 192) xc[pos * 192 + n] = f2bu(v);
                    else         zz[pos * 192 + (n - 192)] = f2bu(v);
                } else if constexpr (EPI == 1) {
                    if (n < 152) ((float*)out0v)[pos * 152 + n] = v;
                } else if constexpr (EPI == 2) {
                    if (n < 96) ((float*)out0v)[pos * 96 + n] = res[pos * 96 + n] + v;
                } else if constexpr (EPI == 3) {
                    ((unsigned short*)out0v)[pos * 384 + n] = f2bu(geluf(v + bias[n]));
                } else {
                    if (n < 96) ((float*)out0v)[pos * 96 + n] =
                        res[pos * 96 + n] + bias[n] + v;
                }
            }
        }
    }
}

// ---- K2: depthwise 3x3 conv + bias + silu, 4 channels/thread ---------------
__global__ __launch_bounds__(256) void k2_conv(
    const unsigned short* __restrict__ xcpre, const float* __restrict__ cw,
    const float* __restrict__ cb, unsigned short* __restrict__ xconv) {
    int idx = blockIdx.x * 256 + threadIdx.x;
    int dd = idx % 48;
    int P = idx / 48;
    int d0 = dd * 4;
    int b = P / LLEN, l = P - b * LLEN;
    int h = l / WWW, w = l - h * WWW;
    float acc0 = cb[d0], acc1 = cb[d0 + 1], acc2 = cb[d0 + 2], acc3 = cb[d0 + 3];
#pragma unroll
    for (int i = 0; i < 3; ++i) {
        int hh = h + i - 1;
        if (hh < 0 || hh >= HHH) continue;
#pragma unroll
        for (int j = 0; j < 3; ++j) {
            int ww = w + j - 1;
            if (ww < 0 || ww >= WWW) continue;
            ushort4 xv = *(const ushort4*)&xcpre[
                ((size_t)(b * LLEN + hh * WWW + ww)) * DIN + d0];
            acc0 = fmaf(bu2f(xv.x), cw[(d0 + 0) * 9 + i * 3 + j], acc0);
            acc1 = fmaf(bu2f(xv.y), cw[(d0 + 1) * 9 + i * 3 + j], acc1);
            acc2 = fmaf(bu2f(xv.z), cw[(d0 + 2) * 9 + i * 3 + j], acc2);
            acc3 = fmaf(bu2f(xv.w), cw[(d0 + 3) * 9 + i * 3 + j], acc3);
        }
    }
    acc0 = acc0 * sigm(acc0); acc1 = acc1 * sigm(acc1);
    acc2 = acc2 * sigm(acc2); acc3 = acc3 * sigm(acc3);
    ushort4 o;
    o.x = f2bu(acc0); o.y = f2bu(acc1); o.z = f2bu(acc2); o.w = f2bu(acc3);
    *(ushort4*)&xconv[(size_t)P * DIN + d0] = o;
}

// ---- K4: scan pass 1 — one segment per block, packed-fp32, fp32 h-out ------
__global__ __launch_bounds__(192) void k4_scan1(
    const bf16* __restrict__ xconv, const float* __restrict__ proj,
    const float* __restrict__ dtw, const float* __restrict__ dtb,
    const float* __restrict__ a2g, float* __restrict__ hloc,
    float* __restrict__ tsum) {
    __shared__ float pl[SEGL * PJS1];
    __shared__ int posl[SEGL];
    const int bid = blockIdx.x;              // 3584 = (b*4+k)*112 + s
    const int s = bid % SSEG;
    const int bk = bid / SSEG;
    const int k = bk & 3, b = bk >> 2;
    const int d = threadIdx.x;
    const int l0 = s * SEGL;
    for (int q = d; q < SEGL * 22; q += 192) {
        int st = q / 22, c = q - st * 22;
        int p = pos_map(k, l0 + st);
        int ofs = (c < 6) ? c : c + 2;
        pl[st * PJS1 + ofs] = proj[(size_t)(b * LLEN + p) * PJW + k * PJC + c];
    }
    if (d < SEGL) posl[d] = pos_map(k, l0 + d) * DIN;
    float w6[RDT];
#pragma unroll
    for (int r = 0; r < RDT; ++r) w6[r] = dtw[(k * DIN + d) * RDT + r];
    const float bias = dtb[k * DIN + d];
    float2 a2[8];
#pragma unroll
    for (int j = 0; j < 8; ++j)
        a2[j] = *(const float2*)&a2g[(k * DIN + d) * NST + 2 * j];
    float2 h2[8];
#pragma unroll
    for (int j = 0; j < 8; ++j) h2[j] = make_float2(0.f, 0.f);
    float T = 0.f;
    __syncthreads();
    const bf16* xg = xconv + (size_t)b * LLEN * DIN + d;
    for (int bt = 0; bt < 4; ++bt) {
        int off7[7]; float xv7[7];
#pragma unroll
        for (int i = 0; i < 7; ++i) off7[i] = posl[bt * 7 + i];
#pragma unroll
        for (int i = 0; i < 7; ++i) xv7[i] = b2f(xg[off7[i]]);
#pragma unroll
        for (int i = 0; i < 7; ++i) {
            const float* rowf = &pl[(bt * 7 + i) * PJS1];
            float4 g0 = *(const float4*)(rowf);
            float2 g1 = *(const float2*)(rowf + 4);
            float dtv = bias;
            dtv = fmaf(g0.x, w6[0], dtv); dtv = fmaf(g0.y, w6[1], dtv);
            dtv = fmaf(g0.z, w6[2], dtv); dtv = fmaf(g0.w, w6[3], dtv);
            dtv = fmaf(g1.x, w6[4], dtv); dtv = fmaf(g1.y, w6[5], dtv);
            dtv = softplusf(dtv);
            T += dtv;
            float2 dt2 = make_float2(dtv, dtv);
            float2 u2 = make_float2(dtv * xv7[i], dtv * xv7[i]);
#pragma unroll
            for (int g = 0; g < 4; ++g) {
                float4 Bv = *(const float4*)(rowf + 8 + 4 * g);
                float2 Blo = make_float2(Bv.x, Bv.y);
                float2 Bhi = make_float2(Bv.z, Bv.w);
                float2 alo = pk_mul(dt2, a2[2 * g]);
                float2 ahi = pk_mul(dt2, a2[2 * g + 1]);
                float2 elo, ehi;
                elo.x = EXP2F(alo.x); elo.y = EXP2F(alo.y);
                ehi.x = EXP2F(ahi.x); ehi.y = EXP2F(ahi.y);
                h2[2 * g]     = pk_fma(h2[2 * g],     elo, pk_mul(u2, Blo));
                h2[2 * g + 1] = pk_fma(h2[2 * g + 1], ehi, pk_mul(u2, Bhi));
            }
        }
    }
    size_t base = ((size_t)bid * DIN + d) * NST;
#pragma unroll
    for (int j = 0; j < 8; ++j) *(float2*)&hloc[base + 2 * j] = h2[j];
    tsum[bid * DIN + d] = T;
}

// ---- K5: exact segment carries, 8-segment batched loads --------------------
// hin aliases hloc (read-before-write). Batching: all 8 loads of a batch
// issue before any of its 8 stores — bitwise identical semantics to the
// serial loop, but 8-deep memory-level parallelism.
__global__ __launch_bounds__(256) void k5_carry(
    const float* hloc, const float* __restrict__ tsum,
    const float* __restrict__ a2g, float* hin) {
    int g = blockIdx.x * 256 + threadIdx.x;   // over B*K*D*N
    int n = g & 15;
    int dk = g >> 4;
    int d = dk % DIN;
    int bk = dk / DIN;                        // b*4 + k
    int k = bk & 3;
    float a2 = a2g[(k * DIN + d) * NST + n];
    float Hc = 0.f;
    for (int s0 = 0; s0 < SSEG; s0 += 8) {
        float hl[8], Tv[8];
#pragma unroll
        for (int j = 0; j < 8; ++j) {
            int bid = bk * SSEG + s0 + j;
            size_t idx = ((size_t)bid * DIN + d) * NST + n;
            hl[j] = hloc[idx];
            Tv[j] = tsum[bid * DIN + d];
        }
        float dec[8];
#pragma unroll
        for (int j = 0; j < 8; ++j) dec[j] = EXP2F(a2 * Tv[j]);
        float out[8];
#pragma unroll
        for (int j = 0; j < 8; ++j) {
            out[j] = Hc;
            Hc = fmaf(dec[j], Hc, hl[j]);
        }
#pragma unroll
        for (int j = 0; j < 8; ++j) {
            int bid = bk * SSEG + s0 + j;
            size_t idx = ((size_t)bid * DIN + d) * NST + n;
            hin[idx] = out[j];
        }
    }
}

// ---- K6: scan pass 2 — one segment per block, packed-fp32, fp32 h-in -------
__global__ __launch_bounds__(192) void k6_scan2(
    const bf16* __restrict__ xconv, const float* __restrict__ proj,
    const float* __restrict__ dtw, const float* __restrict__ dtb,
    const float* __restrict__ a2g, const float* __restrict__ Dsp,
    const float* __restrict__ hin, bf16* __restrict__ ysm) {
    __shared__ float pl[SEGL * PJS];
    __shared__ int posl[SEGL];
    const int bid = blockIdx.x;
    const int s = bid % SSEG;
    const int bk = bid / SSEG;
    const int k = bk & 3, b = bk >> 2;
    const int d = threadIdx.x;
    const int l0 = s * SEGL;
    for (int q = d; q < SEGL * PJC; q += 192) {
        int st = q / PJC, c = q - st * PJC;
        int p = pos_map(k, l0 + st);
        int ofs = (c < 6) ? c : c + 2;
        pl[st * PJS + ofs] = proj[(size_t)(b * LLEN + p) * PJW + k * PJC + c];
    }
    if (d < SEGL) posl[d] = pos_map(k, l0 + d) * DIN;
    float w6[RDT];
#pragma unroll
    for (int r = 0; r < RDT; ++r) w6[r] = dtw[(k * DIN + d) * RDT + r];
    const float bias = dtb[k * DIN + d];
    const float dsv = Dsp[k * DIN + d];
    float2 a2[8];
#pragma unroll
    for (int j = 0; j < 8; ++j)
        a2[j] = *(const float2*)&a2g[(k * DIN + d) * NST + 2 * j];
    float2 h2[8];
    size_t hbase = ((size_t)bid * DIN + d) * NST;
#pragma unroll
    for (int j = 0; j < 8; ++j) h2[j] = *(const float2*)&hin[hbase + 2 * j];
    __syncthreads();
    const bf16* xg = xconv + (size_t)b * LLEN * DIN + d;
    bf16* ysg = ysm + ((size_t)bk * LLEN) * DIN + d;
    for (int bt = 0; bt < 4; ++bt) {
        int off7[7]; float xv7[7];
#pragma unroll
        for (int i = 0; i < 7; ++i) off7[i] = posl[bt * 7 + i];
#pragma unroll
        for (int i = 0; i < 7; ++i) xv7[i] = b2f(xg[off7[i]]);
#pragma unroll
        for (int i = 0; i < 7; ++i) {
            const float* rowf = &pl[(bt * 7 + i) * PJS];
            float4 g0 = *(const float4*)(rowf);
            float2 g1 = *(const float2*)(rowf + 4);
            float dtv = bias;
            dtv = fmaf(g0.x, w6[0], dtv); dtv = fmaf(g0.y, w6[1], dtv);
            dtv = fmaf(g0.z, w6[2], dtv); dtv = fmaf(g0.w, w6[3], dtv);
            dtv = fmaf(g1.x, w6[4], dtv); dtv = fmaf(g1.y, w6[5], dtv);
            dtv = softplusf(dtv);
            float2 dt2 = make_float2(dtv, dtv);
            float2 u2 = make_float2(dtv * xv7[i], dtv * xv7[i]);
            float2 yac0 = make_float2(0.f, 0.f), yac1 = make_float2(0.f, 0.f);
#pragma unroll
            for (int g = 0; g < 4; ++g) {
                float4 Bv = *(const float4*)(rowf + 8 + 4 * g);
                float4 Cv = *(const float4*)(rowf + 24 + 4 * g);
                float2 Blo = make_float2(Bv.x, Bv.y);
                float2 Bhi = make_float2(Bv.z, Bv.w);
                float2 Clo = make_float2(Cv.x, Cv.y);
                float2 Chi = make_float2(Cv.z, Cv.w);
                float2 alo = pk_mul(dt2, a2[2 * g]);
                float2 ahi = pk_mul(dt2, a2[2 * g + 1]);
                float2 elo, ehi;
                elo.x = EXP2F(alo.x); elo.y = EXP2F(alo.y);
                ehi.x = EXP2F(ahi.x); ehi.y = EXP2F(ahi.y);
                h2[2 * g]     = pk_fma(h2[2 * g],     elo, pk_mul(u2, Blo));
                h2[2 * g + 1] = pk_fma(h2[2 * g + 1], ehi, pk_mul(u2, Bhi));
                yac0 = pk_fma(h2[2 * g],     Clo, yac0);
                yac1 = pk_fma(h2[2 * g + 1], Chi, yac1);
            }
            float y = (yac0.x + yac0.y) + (yac1.x + yac1.y);
            ysg[off7[i]] = f2b(fmaf(dsv, xv7[i], y));
        }
    }
}

// ---- K6.5: merge 4 planes + out_norm LN + *silu(z), 8-wide bf16 vecio ------
__global__ __launch_bounds__(256) void k65_merge(
    const bf16* __restrict__ ysm, const bf16* __restrict__ z,
    const float* __restrict__ onw, const float* __restrict__ onb,
    bf16* __restrict__ ymod) {
    __shared__ float rb[16 * DIN];
    __shared__ float ps[256], pq[256];
    __shared__ float mrow[16], srow[16];
    const int t = threadIdx.x;
    const int P0 = blockIdx.x * 16;
    // fill: 384 groups of 8 channels (uint4 = 8 bf16 per plane)
    for (int q8 = t; q8 < 16 * DIN / 8; q8 += 256) {
        int pos = q8 / 24, c = (q8 - pos * 24) * 8;
        int P = P0 + pos;
        int b = P / LLEN, l = P - b * LLEN;
        size_t base = ((size_t)(b * KDIR) * LLEN + l) * DIN + c;
        size_t pstr = (size_t)LLEN * DIN;
        uint4 v0 = *(const uint4*)&ysm[base];
        uint4 v1 = *(const uint4*)&ysm[base + pstr];
        uint4 v2 = *(const uint4*)&ysm[base + 2 * pstr];
        uint4 v3 = *(const uint4*)&ysm[base + 3 * pstr];
        const unsigned short* u0 = (const unsigned short*)&v0;
        const unsigned short* u1 = (const unsigned short*)&v1;
        const unsigned short* u2 = (const unsigned short*)&v2;
        const unsigned short* u3 = (const unsigned short*)&v3;
        float o[8];
#pragma unroll
        for (int j = 0; j < 8; ++j)
            o[j] = bu2f(u0[j]) + bu2f(u1[j]) + bu2f(u2[j]) + bu2f(u3[j]);
        *(float4*)&rb[pos * DIN + c]     = make_float4(o[0], o[1], o[2], o[3]);
        *(float4*)&rb[pos * DIN + c + 4] = make_float4(o[4], o[5], o[6], o[7]);
    }
    __syncthreads();
    {
        int pos = t >> 4, part = t & 15;
        float s = 0.f, s2 = 0.f;
        for (int i = 0; i < 12; ++i) {
            float v = rb[pos * DIN + part * 12 + i];
            s += v; s2 += v * v;
        }
        ps[pos * 16 + part] = s; pq[pos * 16 + part] = s2;
    }
    __syncthreads();
    if (t < 16) {
        float s = 0.f, s2 = 0.f;
        for (int i = 0; i < 16; ++i) { s += ps[t * 16 + i]; s2 += pq[t * 16 + i]; }
        float m = s * (1.f / DIN);
        float v = s2 * (1.f / DIN) - m * m;
        mrow[t] = m; srow[t] = rsqrtf(v + 1e-5f);
    }
    __syncthreads();
    for (int q8 = t; q8 < 16 * DIN / 8; q8 += 256) {
        int pos = q8 / 24, c = (q8 - pos * 24) * 8;
        int P = P0 + pos;
        float m = mrow[pos], sr = srow[pos];
        uint4 zv4 = *(const uint4*)&z[(size_t)P * DIN + c];
        const unsigned short* zu = (const unsigned short*)&zv4;
        unsigned short ou[8];
#pragma unroll
        for (int j = 0; j < 8; ++j) {
            float v = (rb[pos * DIN + c + j] - m) * sr * onw[c + j] + onb[c + j];
            float zv = bu2f(zu[j]);
            v *= zv * sigm(zv);
            ou[j] = f2bu(v);
        }
        *(uint4*)&ymod[(size_t)P * DIN + c] = *(const uint4*)ou;
    }
}

extern "C" void kernel_launch(void* const* d_in, const int* in_sizes, int n_in,
                              void* d_out, int out_size, void* d_ws, size_t ws_size,
                              hipStream_t stream) {
    const float* x      = (const float*)d_in[0];
    const float* ln1w   = (const float*)d_in[1];
    const float* ln1b   = (const float*)d_in[2];
    const float* inpW   = (const float*)d_in[3];
    const float* convW  = (const float*)d_in[4];
    const float* convB  = (const float*)d_in[5];
    const float* xprojW = (const float*)d_in[6];
    const float* dtW    = (const float*)d_in[7];
    const float* dtB    = (const float*)d_in[8];
    const float* Alog   = (const float*)d_in[9];
    const float* Dsp    = (const float*)d_in[10];
    const float* onw    = (const float*)d_in[11];
    const float* onb    = (const float*)d_in[12];
    const float* outW   = (const float*)d_in[13];
    const float* ln2w   = (const float*)d_in[14];
    const float* ln2b   = (const float*)d_in[15];
    const float* fc1W   = (const float*)d_in[16];
    const float* fc1b   = (const float*)d_in[17];
    const float* fc2W   = (const float*)d_in[18];
    const float* fc2b   = (const float*)d_in[19];
    float* out = (float*)d_out;

    char* ws = (char*)d_ws;
    // layout (byte offsets; lifetimes verified stage-by-stage):
    unsigned short* z_us    = (unsigned short*)(ws + 0);          // [G1..k65]   9,633,792
    bf16*  z_bf             = (bf16*)z_us;
    bf16*  xconv_bf         = (bf16*)(ws + 9633792);              // [k2..k6]    9,633,792
    float* proj_f           = (float*)(ws + 19267584);            // [G2..k6]   15,253,504
    bf16*  ymod_bf          = (bf16*)(ws + 19267584);             // [k65..G3]  alias proj
    float* tsum_f           = (float*)(ws + 34521088);            // [k4..k5]    2,752,512
    unsigned short* xcpre_us= (unsigned short*)(ws + 39337984);   // [G1..k2]    9,633,792
    float* hloc_f           = (float*)(ws + 39337984);            // [k4..k6]   44,040,192 (alias dead xcpre)
    float* hin_f            = hloc_f;                             // k5 r-b-w alias
    float* y1_f             = (float*)(ws + 39337984);            // [G3..G5]   alias dead hloc
    bf16*  ysm_bf           = (bf16*)(ws + 83378176);             // [k6..k65]  38,535,168
    unsigned short* hmlp_us = (unsigned short*)(ws + 83378176);   // [G4..G5]   alias dead ysm
    unsigned short* xbf_us  = (unsigned short*)(ws + 110000000);  // [k1..G1]    4,816,896 (dead ysm zone)
    unsigned short* y1bf_us = (unsigned short*)(ws + 110000000);  // [k1b..G4]  alias (disjoint lifetime)
    float* a2g_f            = (float*)(ws + 121913344);           // [k0..k6]   49,152
    unsigned short* wbf_us  = (unsigned short*)(ws + 121962496);  // [k0w..G5]  316,416 (end 122,278,912)

    k0_pre<<<48, 256, 0, stream>>>(Alog, a2g_f);
    k0w<<<618, 256, 0, stream>>>(inpW, xprojW, outW, fc1W, fc2W, wbf_us);
    k1_ln<<<196, 256, 0, stream>>>(x, ln1w, ln1b, xbf_us);
    gemm_mfma<384, 96, 0, false><<<dim3(196, 6), 256, 0, stream>>>(
        xbf_us, wbf_us + 0, nullptr, nullptr, nullptr, nullptr, xcpre_us, z_us);
    k2_conv<<<4704, 256, 0, stream>>>(xcpre_us, convW, convB,
                                      (unsigned short*)xconv_bf);
    gemm_mfma<152, 192, 1, false><<<dim3(196, 3), 256, 0, stream>>>(
        xconv_bf, wbf_us + 36864, nullptr, nullptr, nullptr, nullptr,
        proj_f, nullptr);
    k4_scan1<<<3584, 192, 0, stream>>>(xconv_bf, proj_f, dtW, dtB, a2g_f,
                                       hloc_f, tsum_f);
    k5_carry<<<384, 256, 0, stream>>>(hloc_f, tsum_f, a2g_f, hin_f);
    k6_scan2<<<3584, 192, 0, stream>>>(xconv_bf, proj_f, dtW, dtB, a2g_f, Dsp,
                                       hin_f, ysm_bf);
    k65_merge<<<1568, 256, 0, stream>>>(ysm_bf, z_bf, onw, onb, ymod_bf);
    gemm_mfma<96, 192, 2, false><<<dim3(196, 2), 256, 0, stream>>>(
        ymod_bf, wbf_us + 66048, nullptr, x, nullptr, nullptr, y1_f, nullptr);
    k1_ln<<<196, 256, 0, stream>>>(y1_f, ln2w, ln2b, y1bf_us);
    gemm_mfma<384, 96, 3, false><<<dim3(196, 6), 256, 0, stream>>>(
        y1bf_us, wbf_us + 84480, fc1b, nullptr, nullptr, nullptr, hmlp_us,
        nullptr);
    gemm_mfma<96, 384, 4, false><<<dim3(196, 2), 256, 0, stream>>>(
        hmlp_us, wbf_us + 121344, fc2b, y1_f, nullptr, nullptr, out, nullptr);
}